// Round 5
// baseline (497.372 us; speedup 1.0000x reference)
//
#include <hip/hip_runtime.h>

// Problem constants (from reference)
#define C_IMG 16
#define GRIDSZ 128
#define VOL (GRIDSZ * GRIDSZ * GRIDSZ)
#define SLOPE 0.3f
#define SCALE 0.1f
#define EPB 4096         // edges per k_bucket block
#define CAPB 12288       // fixed pair-region capacity per 512-vtx bucket (mean 8192, sd ~90)
#define BIN_CAP 16384    // binsort LDS staging capacity

using f4_t  = __attribute__((ext_vector_type(4))) float;
using bf8_t = __attribute__((ext_vector_type(8))) short;

// bf16 helpers (manual, RNE pack / shift unpack)
__device__ __forceinline__ unsigned int bf16_pack2(float a, float b) {
    unsigned int ua = __float_as_uint(a);
    ua = (ua + 0x7FFFu + ((ua >> 16) & 1u)) >> 16;
    unsigned int ub = __float_as_uint(b);
    ub = (ub + 0x7FFFu + ((ub >> 16) & 1u)) >> 16;
    return ua | (ub << 16);
}
__device__ __forceinline__ unsigned short bf16_1(float a) {
    unsigned int ua = __float_as_uint(a);
    return (unsigned short)((ua + 0x7FFFu + ((ua >> 16) & 1u)) >> 16);
}
__device__ __forceinline__ float bf_lo(unsigned int u) { return __uint_as_float(u << 16); }
__device__ __forceinline__ float bf_hi(unsigned int u) { return __uint_as_float(u & 0xFFFF0000u); }

// fp8 e4m3fn helpers (software; decode via bf16-bitfield trick, RNE encode).
// Gather tables only — MFMA inputs stay bf16.
__device__ __forceinline__ float fp8_dec(unsigned int b) {
    unsigned int em = b & 0x7Fu;
    unsigned int bf = ((b & 0x80u) << 8) | ((em << 4) + 0x3C00u);
    if (em < 8u) bf = (b & 0x80u) << 8;   // exp==0: flush subnormals to +-0
    return __uint_as_float(bf << 16);
}
__device__ __forceinline__ unsigned int fp8_enc(float f) {
    unsigned int u = __float_as_uint(f);
    unsigned int s = (u >> 24) & 0x80u;
    int e = (int)((u >> 23) & 0xFFu) - 127 + 7;
    unsigned int m = (u >> 20) & 0x7u;
    unsigned int rem = u & 0xFFFFFu;
    m += (rem > 0x80000u || (rem == 0x80000u && (m & 1u))) ? 1u : 0u;
    if (m == 8u) { m = 0u; e += 1; }
    if (e <= 0) return s;               // flush to signed zero
    if (e > 15) { e = 15; m = 6u; }     // clamp to 448
    if (e == 15 && m == 7u) m = 6u;     // avoid NaN encoding
    return s | ((unsigned)e << 3) | m;
}
__device__ __forceinline__ void acc4(float* a, unsigned int w) {
    a[0] += fp8_dec(w & 0xFFu);
    a[1] += fp8_dec((w >> 8) & 0xFFu);
    a[2] += fp8_dec((w >> 16) & 0xFFu);
    a[3] += fp8_dec(w >> 24);
}

// ---------------------------------------------------------------------------
// Image transpose: img[16][128][128][128] fp32 -> timg[x][y][z][16] bf16.
__global__ __launch_bounds__(256) void k_transpose(const float* __restrict__ img,
                                                   unsigned int* __restrict__ timg) {
    const int t = blockIdx.x * 256 + threadIdx.x;   // [0, VOL/2)
    const int zp = t & 63;                          // z pair index
    const int xy = t >> 6;                          // x*128+y
    const size_t ibase = (size_t)xy * GRIDSZ + 2 * zp;
    float2 c[16];
    #pragma unroll
    for (int ch = 0; ch < 16; ++ch)
        c[ch] = *(const float2*)(img + (size_t)ch * VOL + ibase);
    uint4 o0a, o0b, o1a, o1b;
    o0a.x = bf16_pack2(c[0].x,  c[1].x);  o0a.y = bf16_pack2(c[2].x,  c[3].x);
    o0a.z = bf16_pack2(c[4].x,  c[5].x);  o0a.w = bf16_pack2(c[6].x,  c[7].x);
    o0b.x = bf16_pack2(c[8].x,  c[9].x);  o0b.y = bf16_pack2(c[10].x, c[11].x);
    o0b.z = bf16_pack2(c[12].x, c[13].x); o0b.w = bf16_pack2(c[14].x, c[15].x);
    o1a.x = bf16_pack2(c[0].y,  c[1].y);  o1a.y = bf16_pack2(c[2].y,  c[3].y);
    o1a.z = bf16_pack2(c[4].y,  c[5].y);  o1a.w = bf16_pack2(c[6].y,  c[7].y);
    o1b.x = bf16_pack2(c[8].y,  c[9].y);  o1b.y = bf16_pack2(c[10].y, c[11].y);
    o1b.z = bf16_pack2(c[12].y, c[13].y); o1b.w = bf16_pack2(c[14].y, c[15].y);
    unsigned int* po = timg + (size_t)(xy * GRIDSZ + 2 * zp) * 8;
    *(uint4*)(po + 0)  = o0a;
    *(uint4*)(po + 4)  = o0b;
    *(uint4*)(po + 8)  = o1a;
    *(uint4*)(po + 12) = o1b;
}

// ---------------------------------------------------------------------------
// Single-pass bucketing into FIXED-CAPACITY per-bucket regions.
// Packed pair: (src<<9)|(dst&511) — src<2^17.
__global__ __launch_bounds__(256) void k_bucket(const int* __restrict__ esrc,
                                                const int* __restrict__ edst,
                                                int* __restrict__ bucketCursor,
                                                unsigned int* __restrict__ pairs,
                                                int* __restrict__ rowStart,
                                                int ne, int nv) {
    __shared__ unsigned int hist[256];
    __shared__ unsigned int pref[256];
    __shared__ unsigned int curs[256];
    __shared__ unsigned int gbase[256];
    __shared__ unsigned int stage_v[EPB];
    __shared__ unsigned char stage_b[EPB];
    const int tid = threadIdx.x;
    const int base = blockIdx.x * EPB;
    const int n = min(EPB, ne - base);
    if (blockIdx.x == 0 && tid == 0) rowStart[nv] = ne;
    hist[tid] = 0;
    __syncthreads();
    for (int i = tid; i < n; i += 256)
        atomicAdd(&hist[((unsigned)edst[base + i]) >> 9], 1u);
    __syncthreads();
    const unsigned int h = hist[tid];
    pref[tid] = h;
    __syncthreads();
    #pragma unroll
    for (int off = 1; off < 256; off <<= 1) {
        unsigned int t = (tid >= off) ? pref[tid - off] : 0;
        __syncthreads();
        pref[tid] += t;
        __syncthreads();
    }
    const unsigned int excl = pref[tid] - h;
    if (h) {
        int pos = atomicAdd(&bucketCursor[tid], (int)h);
        if (pos > CAPB - (int)h) pos = CAPB - (int)h;  // statistically unreachable guard
        gbase[tid] = (unsigned int)(tid * CAPB + pos);
    } else {
        gbase[tid] = 0u;
    }
    __syncthreads();
    pref[tid] = excl;
    curs[tid] = excl;
    __syncthreads();
    for (int i = tid; i < n; i += 256) {
        unsigned int d = (unsigned)edst[base + i];
        unsigned int s = (unsigned)esrc[base + i];
        unsigned int p = atomicAdd(&curs[d >> 9], 1u);
        stage_v[p] = (s << 9) | (d & 511u);
        stage_b[p] = (unsigned char)(d >> 9);
    }
    __syncthreads();
    for (int i = tid; i < n; i += 256) {
        unsigned int b = stage_b[i];
        pairs[gbase[b] + (unsigned)i - pref[b]] = stage_v[i];
    }
}

// Within-bucket sort -> dense csrSrc + rowStart + invdeg.
__global__ __launch_bounds__(256) void k_binsort(const unsigned int* __restrict__ pairs,
                                                 const int* __restrict__ bucketCursor,
                                                 int* __restrict__ rowStart,
                                                 float* __restrict__ invdeg,
                                                 int* __restrict__ csrSrc, int nv) {
    __shared__ int deg_s[512];
    __shared__ int rs_s[512];
    __shared__ int cur_s[512];
    __shared__ int scan_s[256];
    __shared__ int bb[256];
    __shared__ int outbuf[BIN_CAP];
    const int tid = threadIdx.x;
    const int b = blockIdx.x;
    const int vbase = b << 9;
    if (vbase >= nv) return;
    const int nvb = min(512, nv - vbase);
    const int c = min(bucketCursor[tid], CAPB);
    bb[tid] = c;
    deg_s[tid] = 0;
    deg_s[tid + 256] = 0;
    __syncthreads();
    #pragma unroll
    for (int off = 1; off < 256; off <<= 1) {
        int t = (tid >= off) ? bb[tid - off] : 0;
        __syncthreads();
        bb[tid] += t;
        __syncthreads();
    }
    const int count = min(bucketCursor[b], CAPB);
    const int gs = bb[b] - count;
    const unsigned int* pbase = pairs + (size_t)b * CAPB;
    for (int i = tid; i < count; i += 256) {
        unsigned int p = pbase[i];
        atomicAdd(&deg_s[p & 511u], 1);
    }
    __syncthreads();
    const int d0 = deg_s[2 * tid];
    const int d1 = deg_s[2 * tid + 1];
    const int ps = d0 + d1;
    scan_s[tid] = ps;
    __syncthreads();
    #pragma unroll
    for (int off = 1; off < 256; off <<= 1) {
        int t = (tid >= off) ? scan_s[tid - off] : 0;
        __syncthreads();
        scan_s[tid] += t;
        __syncthreads();
    }
    const int epair = scan_s[tid] - ps;
    rs_s[2 * tid] = epair;
    rs_s[2 * tid + 1] = epair + d0;
    cur_s[2 * tid] = epair;
    cur_s[2 * tid + 1] = epair + d0;
    #pragma unroll
    for (int u = 0; u < 2; ++u) {
        int idx = 2 * tid + u;
        if (idx < nvb) {
            rowStart[vbase + idx] = gs + rs_s[idx];
            int d = deg_s[idx];
            invdeg[vbase + idx] = 1.0f / (float)(d > 1 ? d : 1);
        }
    }
    __syncthreads();
    for (int i = tid; i < count; i += 256) {
        unsigned int p = pbase[i];
        int pos = atomicAdd(&cur_s[p & 511u], 1);
        outbuf[pos] = (int)(p >> 9);
    }
    __syncthreads();
    for (int i = tid; i < count; i += 256) csrSrc[gs + i] = outbuf[i];
}

// ---------------------------------------------------------------------------
// Trilinear sample -> bf16 feats rows (stride 16u: [ch16, pos3, 0...]) AND
// fp8 feats8 rows (stride 32B, same column order) for the gather path.
__global__ __launch_bounds__(256) void k_sample(const unsigned int* __restrict__ timg,
                                                const float* __restrict__ verts,
                                                unsigned int* __restrict__ feats,
                                                unsigned char* __restrict__ feats8, int nv) {
    int t = blockIdx.x * 256 + threadIdx.x;
    int v = t >> 1;
    int q = t & 1;          // channel group: q*8 .. q*8+7
    if (v >= nv) return;
    float px = verts[v * 3 + 0];
    float py = verts[v * 3 + 1];
    float pz = verts[v * 3 + 2];
    float cx = fminf(fmaxf(px, 0.0f), 127.0f);
    float cy = fminf(fmaxf(py, 0.0f), 127.0f);
    float cz = fminf(fmaxf(pz, 0.0f), 127.0f);
    float fx = floorf(cx), fy = floorf(cy), fz = floorf(cz);
    int x0 = (int)fx, y0 = (int)fy, z0 = (int)fz;
    int x1 = min(x0 + 1, 127), y1 = min(y0 + 1, 127), z1 = min(z0 + 1, 127);
    float wx = cx - fx, wy = cy - fy, wz = cz - fz;
    const int qo = q * 4;
    #define LD(X, Y, Z) (*(const uint4*)(timg + ((size_t)((((X) << 7) + (Y)) << 7) + (size_t)(Z)) * 8 + qo))
    uint4 f000 = LD(x0, y0, z0), f001 = LD(x0, y0, z1);
    uint4 f010 = LD(x0, y1, z0), f011 = LD(x0, y1, z1);
    uint4 f100 = LD(x1, y0, z0), f101 = LD(x1, y0, z1);
    uint4 f110 = LD(x1, y1, z0), f111 = LD(x1, y1, z1);
    #undef LD
    float r[8];
    const unsigned int* a000 = (const unsigned int*)&f000;
    const unsigned int* a001 = (const unsigned int*)&f001;
    const unsigned int* a010 = (const unsigned int*)&f010;
    const unsigned int* a011 = (const unsigned int*)&f011;
    const unsigned int* a100 = (const unsigned int*)&f100;
    const unsigned int* a101 = (const unsigned int*)&f101;
    const unsigned int* a110 = (const unsigned int*)&f110;
    const unsigned int* a111 = (const unsigned int*)&f111;
    #pragma unroll
    for (int u = 0; u < 4; ++u) {
        float c00l = bf_lo(a000[u]) * (1.f - wz) + bf_lo(a001[u]) * wz;
        float c01l = bf_lo(a010[u]) * (1.f - wz) + bf_lo(a011[u]) * wz;
        float c10l = bf_lo(a100[u]) * (1.f - wz) + bf_lo(a101[u]) * wz;
        float c11l = bf_lo(a110[u]) * (1.f - wz) + bf_lo(a111[u]) * wz;
        r[2 * u] = (c00l * (1.f - wy) + c01l * wy) * (1.f - wx) +
                   (c10l * (1.f - wy) + c11l * wy) * wx;
        float c00h = bf_hi(a000[u]) * (1.f - wz) + bf_hi(a001[u]) * wz;
        float c01h = bf_hi(a010[u]) * (1.f - wz) + bf_hi(a011[u]) * wz;
        float c10h = bf_hi(a100[u]) * (1.f - wz) + bf_hi(a101[u]) * wz;
        float c11h = bf_hi(a110[u]) * (1.f - wz) + bf_hi(a111[u]) * wz;
        r[2 * u + 1] = (c00h * (1.f - wy) + c01h * wy) * (1.f - wx) +
                       (c10h * (1.f - wy) + c11h * wy) * wx;
    }
    unsigned int* row = feats + (size_t)v * 16;
    uint4 o;
    o.x = bf16_pack2(r[0], r[1]); o.y = bf16_pack2(r[2], r[3]);
    o.z = bf16_pack2(r[4], r[5]); o.w = bf16_pack2(r[6], r[7]);
    *(uint4*)(row + q * 4) = o;
    // fp8 mirror row (32B): bytes [q*8, q*8+8) = channels
    unsigned int w0 = fp8_enc(r[0]) | (fp8_enc(r[1]) << 8) |
                      (fp8_enc(r[2]) << 16) | (fp8_enc(r[3]) << 24);
    unsigned int w1 = fp8_enc(r[4]) | (fp8_enc(r[5]) << 8) |
                      (fp8_enc(r[6]) << 16) | (fp8_enc(r[7]) << 24);
    *(uint2*)(feats8 + (size_t)v * 32 + q * 8) = make_uint2(w0, w1);
    if (q == 0) {
        uint4 o2;
        o2.x = bf16_pack2(px * (1.0f / 128.0f), py * (1.0f / 128.0f));
        o2.y = bf16_pack2(pz * (1.0f / 128.0f), 0.0f);
        o2.z = 0u; o2.w = 0u;
        *(uint4*)(row + 8) = o2;
        *(uint4*)(row + 12) = make_uint4(0u, 0u, 0u, 0u);
        unsigned int wp = fp8_enc(px * (1.0f / 128.0f)) |
                          (fp8_enc(py * (1.0f / 128.0f)) << 8) |
                          (fp8_enc(pz * (1.0f / 128.0f)) << 16);
        *(uint4*)(feats8 + (size_t)v * 32 + 16) = make_uint4(wp, 0u, 0u, 0u);
    }
}

// ---------------------------------------------------------------------------
// FUSED gather + MFMA edge-conv. Gather reads the FP8 table g8 (row stride =
// KX bytes); accumulates fp32; writes bf16 nb tile to LDS. MFMA self-path
// reads bf16 x. EMIT8: epilogue also writes fp8 copy of the output (next
// layer's gather table). PREMUL (layer 2): emit z = act(h3) @ Wn3.
template <int KX, int COUT, bool REMAP0, int VALID_CIN, bool PREMUL, bool EMIT8>
__global__ __launch_bounds__(256) void k_layer_fused(const unsigned int* __restrict__ x,
                                                     const unsigned char* __restrict__ g8,
                                                     const int* __restrict__ rowStart,
                                                     const int* __restrict__ csrSrc,
                                                     const float* __restrict__ invdeg,
                                                     const float* __restrict__ Ws,
                                                     const float* __restrict__ Wn,
                                                     const float* __restrict__ bias,
                                                     unsigned int* __restrict__ out,
                                                     unsigned char* __restrict__ out8,
                                                     int nv,
                                                     const float* __restrict__ Wn3,
                                                     unsigned int* __restrict__ zout) {
    constexpr int KTOT = 2 * KX;
    constexpr int KW = KTOT + 8;      // weight LDS row stride (bf16), bank-rotating
    constexpr int NT = COUT / 16;     // n-tiles per wave
    constexpr int MT = 2;             // m-tiles per wave (32 vertices)
    constexpr int SXU = KX / 2;       // x row stride in uints
    constexpr int KS = KX / 32;       // k-steps per source
    constexpr int VPB = 128;          // vertices per block
    constexpr int NCH8 = KX / 16;     // 16-byte (16-channel) fp8 chunks per row
    constexpr int NBW = KX + 8;       // nb_s row stride (bf16 elems)
    __shared__ __align__(16) unsigned short bt[COUT * KW];
    __shared__ __align__(16) unsigned short nb_s[VPB * NBW];
    __shared__ float wn3_s[192];

    // Stage weights: bt[c][kk], kk<KX -> Ws, else Wn.
    for (int i = threadIdx.x; i < COUT * KTOT; i += 256) {
        int c = i / KTOT;
        int kk = i - c * KTOT;
        int j = (kk < KX) ? kk : kk - KX;
        const float* W = (kk < KX) ? Ws : Wn;
        float w = 0.f;
        if (j < VALID_CIN) {
            int sr = REMAP0 ? ((j < 16) ? (j + 3) : (j - 16)) : j;
            w = W[sr * COUT + c];
        }
        bt[c * KW + kk] = bf16_1(w);
    }
    if constexpr (PREMUL) {
        if (threadIdx.x < 192) wn3_s[threadIdx.x] = Wn3[threadIdx.x];
    }

    // Gather phase: fp8 rows, 16 channels per thread-task.
    const int vb0 = blockIdx.x * VPB;
    for (int task = threadIdx.x; task < VPB * NCH8; task += 256) {
        const int vloc = task / NCH8;
        const int ch = task - vloc * NCH8;
        const int v = vb0 + vloc;
        unsigned short* dst = nb_s + vloc * NBW + ch * 16;
        if (v < nv) {
            int beg = rowStart[v];
            int end = rowStart[v + 1];
            float a[16];
            #pragma unroll
            for (int i = 0; i < 16; ++i) a[i] = 0.f;
            int j = beg;
            for (; j + 3 < end; j += 4) {
                int s0 = csrSrc[j];
                int s1 = csrSrc[j + 1];
                int s2 = csrSrc[j + 2];
                int s3 = csrSrc[j + 3];
                uint4 q0 = ((const uint4*)(g8 + (size_t)s0 * KX))[ch];
                uint4 q1 = ((const uint4*)(g8 + (size_t)s1 * KX))[ch];
                uint4 q2 = ((const uint4*)(g8 + (size_t)s2 * KX))[ch];
                uint4 q3 = ((const uint4*)(g8 + (size_t)s3 * KX))[ch];
                acc4(a + 0, q0.x); acc4(a + 4, q0.y); acc4(a + 8, q0.z); acc4(a + 12, q0.w);
                acc4(a + 0, q1.x); acc4(a + 4, q1.y); acc4(a + 8, q1.z); acc4(a + 12, q1.w);
                acc4(a + 0, q2.x); acc4(a + 4, q2.y); acc4(a + 8, q2.z); acc4(a + 12, q2.w);
                acc4(a + 0, q3.x); acc4(a + 4, q3.y); acc4(a + 8, q3.z); acc4(a + 12, q3.w);
            }
            for (; j < end; ++j) {
                int s = csrSrc[j];
                uint4 q = ((const uint4*)(g8 + (size_t)s * KX))[ch];
                acc4(a + 0, q.x); acc4(a + 4, q.y); acc4(a + 8, q.z); acc4(a + 12, q.w);
            }
            const float id = invdeg[v];
            uint4 o1, o2;
            o1.x = bf16_pack2(a[0] * id, a[1] * id);  o1.y = bf16_pack2(a[2] * id, a[3] * id);
            o1.z = bf16_pack2(a[4] * id, a[5] * id);  o1.w = bf16_pack2(a[6] * id, a[7] * id);
            o2.x = bf16_pack2(a[8] * id, a[9] * id);  o2.y = bf16_pack2(a[10] * id, a[11] * id);
            o2.z = bf16_pack2(a[12] * id, a[13] * id); o2.w = bf16_pack2(a[14] * id, a[15] * id);
            *(uint4*)dst = o1;
            *(uint4*)(dst + 8) = o2;
        } else {
            *(uint4*)dst = make_uint4(0u, 0u, 0u, 0u);
            *(uint4*)(dst + 8) = make_uint4(0u, 0u, 0u, 0u);
        }
    }
    __syncthreads();

    const int lane = threadIdx.x & 63;
    const int wid = threadIdx.x >> 6;
    const int v0 = vb0 + wid * (MT * 16);
    const int row = lane & 15;
    const int kg = lane >> 4;         // k-subgroup: 8 contiguous k at kg*8

    f4_t acc[MT][NT] = {};

    #pragma unroll
    for (int ks = 0; ks < 2 * KS; ++ks) {
        bf8_t afrag[MT];
        if (ks < KS) {
            const int kbase = ks * 32;
            #pragma unroll
            for (int mt = 0; mt < MT; ++mt) {
                int v = v0 + mt * 16 + row;
                v = min(v, nv - 1);   // clamp: duplicate row, masked at store
                afrag[mt] = *(const bf8_t*)(x + (size_t)v * SXU + ((kbase + kg * 8) >> 1));
            }
        } else {
            const int kbase = (ks - KS) * 32;
            #pragma unroll
            for (int mt = 0; mt < MT; ++mt) {
                const int vloc = wid * (MT * 16) + mt * 16 + row;
                afrag[mt] = *(const bf8_t*)(nb_s + vloc * NBW + kbase + kg * 8);
            }
        }
        #pragma unroll
        for (int nt = 0; nt < NT; ++nt) {
            bf8_t bfrag = *(const bf8_t*)(bt + (nt * 16 + row) * KW + ks * 32 + kg * 8);
            #pragma unroll
            for (int mt = 0; mt < MT; ++mt)
                acc[mt][nt] = __builtin_amdgcn_mfma_f32_16x16x32_bf16(afrag[mt], bfrag,
                                                                      acc[mt][nt], 0, 0, 0);
        }
    }

    // Epilogue: bias + leaky relu, bf16 stores (+ fp8 mirror), optional premul.
    unsigned short* po = (unsigned short*)out;
    float bq[NT];
    #pragma unroll
    for (int nt = 0; nt < NT; ++nt) bq[nt] = bias[nt * 16 + row];
    #pragma unroll
    for (int mt = 0; mt < MT; ++mt) {
        #pragma unroll
        for (int r = 0; r < 4; ++r) {
            const int v = v0 + mt * 16 + kg * 4 + r;
            float tv[NT];
            #pragma unroll
            for (int nt = 0; nt < NT; ++nt) {
                float t = acc[mt][nt][r] + bq[nt];
                t = (t >= 0.f) ? t : SLOPE * t;
                tv[nt] = t;
                if (v < nv) {
                    po[(size_t)v * COUT + nt * 16 + row] = bf16_1(t);
                    if constexpr (EMIT8)
                        out8[(size_t)v * COUT + nt * 16 + row] = (unsigned char)fp8_enc(t);
                }
            }
            if constexpr (PREMUL) {
                float z0 = 0.f, z1 = 0.f, z2 = 0.f;
                #pragma unroll
                for (int nt = 0; nt < NT; ++nt) {
                    const float* wr = wn3_s + (nt * 16 + row) * 3;
                    z0 += tv[nt] * wr[0];
                    z1 += tv[nt] * wr[1];
                    z2 += tv[nt] * wr[2];
                }
                #pragma unroll
                for (int m = 1; m < 16; m <<= 1) {
                    z0 += __shfl_xor(z0, m);
                    z1 += __shfl_xor(z1, m);
                    z2 += __shfl_xor(z2, m);
                }
                if (row == 0 && v < nv) {
                    uint2 o;
                    o.x = bf16_pack2(z0, z1);
                    o.y = bf16_pack2(z2, 0.f);
                    *(uint2*)(zout + (size_t)v * 2) = o;
                }
            }
        }
    }
}

// Final (fused z-gather): out = verts + SCALE*(h3@Ws3 + gather(z)*inv_deg + b3)
__global__ __launch_bounds__(256) void k_final(const unsigned int* __restrict__ h,
                                               const unsigned int* __restrict__ z,
                                               const int* __restrict__ rowStart,
                                               const int* __restrict__ csrSrc,
                                               const float* __restrict__ invdeg,
                                               const float* __restrict__ ws,
                                               const float* __restrict__ b,
                                               const float* __restrict__ verts,
                                               float* __restrict__ out, int nv) {
    __shared__ float w_s[64 * 3];
    if (threadIdx.x < 64 * 3) w_s[threadIdx.x] = ws[threadIdx.x];
    __syncthreads();
    int v = blockIdx.x * 256 + threadIdx.x;
    if (v >= nv) return;
    float n0 = 0.f, n1 = 0.f, n2 = 0.f;
    {
        int beg = rowStart[v];
        int end = rowStart[v + 1];
        int j = beg;
        for (; j + 3 < end; j += 4) {
            int s0 = csrSrc[j];
            int s1 = csrSrc[j + 1];
            int s2 = csrSrc[j + 2];
            int s3 = csrSrc[j + 3];
            uint2 q0 = *(const uint2*)(z + (size_t)s0 * 2);
            uint2 q1 = *(const uint2*)(z + (size_t)s1 * 2);
            uint2 q2 = *(const uint2*)(z + (size_t)s2 * 2);
            uint2 q3 = *(const uint2*)(z + (size_t)s3 * 2);
            n0 += bf_lo(q0.x); n1 += bf_hi(q0.x); n2 += bf_lo(q0.y);
            n0 += bf_lo(q1.x); n1 += bf_hi(q1.x); n2 += bf_lo(q1.y);
            n0 += bf_lo(q2.x); n1 += bf_hi(q2.x); n2 += bf_lo(q2.y);
            n0 += bf_lo(q3.x); n1 += bf_hi(q3.x); n2 += bf_lo(q3.y);
        }
        for (; j < end; ++j) {
            int s = csrSrc[j];
            uint2 q = *(const uint2*)(z + (size_t)s * 2);
            n0 += bf_lo(q.x); n1 += bf_hi(q.x); n2 += bf_lo(q.y);
        }
    }
    const uint4* hr = (const uint4*)(h + (size_t)v * 32);
    float a0 = b[0], a1 = b[1], a2 = b[2];
    #pragma unroll
    for (int q = 0; q < 8; ++q) {
        uint4 hv = hr[q];
        float f[8] = {bf_lo(hv.x), bf_hi(hv.x), bf_lo(hv.y), bf_hi(hv.y),
                      bf_lo(hv.z), bf_hi(hv.z), bf_lo(hv.w), bf_hi(hv.w)};
        #pragma unroll
        for (int i = 0; i < 8; ++i) {
            int k = q * 8 + i;
            a0 += f[i] * w_s[k * 3 + 0];
            a1 += f[i] * w_s[k * 3 + 1];
            a2 += f[i] * w_s[k * 3 + 2];
        }
    }
    float id = invdeg[v];
    a0 += n0 * id; a1 += n1 * id; a2 += n2 * id;
    out[(size_t)v * 3 + 0] = verts[(size_t)v * 3 + 0] + SCALE * a0;
    out[(size_t)v * 3 + 1] = verts[(size_t)v * 3 + 1] + SCALE * a1;
    out[(size_t)v * 3 + 2] = verts[(size_t)v * 3 + 2] + SCALE * a2;
}

// ---------------------------------------------------------------------------
extern "C" void kernel_launch(void* const* d_in, const int* in_sizes, int n_in,
                              void* d_out, int out_size, void* d_ws, size_t ws_size,
                              hipStream_t stream) {
    const float* img   = (const float*)d_in[0];
    const float* verts = (const float*)d_in[1];
    const int*   esrc  = (const int*)d_in[2];
    const int*   edst  = (const int*)d_in[3];
    const float* ws0 = (const float*)d_in[4];
    const float* wn0 = (const float*)d_in[5];
    const float* b0  = (const float*)d_in[6];
    const float* ws1 = (const float*)d_in[7];
    const float* wn1 = (const float*)d_in[8];
    const float* b1  = (const float*)d_in[9];
    const float* ws2 = (const float*)d_in[10];
    const float* wn2 = (const float*)d_in[11];
    const float* b2  = (const float*)d_in[12];
    const float* ws3 = (const float*)d_in[13];
    const float* wn3 = (const float*)d_in[14];
    const float* b3  = (const float*)d_in[15];

    const int nv = in_sizes[1] / 3;
    const int ne = in_sizes[2];

    char* base = (char*)d_ws;
    size_t off = 0;
    auto alloc = [&](size_t bytes) -> void* {
        off = (off + 255) & ~(size_t)255;
        void* p = base + off;
        off += bytes;
        return p;
    };
    float* invdeg   = (float*)alloc((size_t)nv * 4);
    int*   rowStart = (int*)alloc((size_t)(nv + 1) * 4);
    int*   bucketCursor = (int*)alloc(256 * 4);
    int*   csrSrc   = (int*)alloc((size_t)ne * 4);
    unsigned int* pairs = (unsigned int*)alloc((size_t)256 * CAPB * 4);
    unsigned int* A   = (unsigned int*)alloc((size_t)nv * 32 * 4);  // feats(16u) then h2(32u)
    unsigned int* B   = (unsigned int*)alloc((size_t)nv * 32 * 4);  // h1(16u) then h3(32u)
    unsigned int* Z   = (unsigned int*)alloc((size_t)nv * 2 * 4);   // bf16 premultiplied
    unsigned char* feats8 = (unsigned char*)alloc((size_t)nv * 32); // fp8 gather tables
    unsigned char* h1_8   = (unsigned char*)alloc((size_t)nv * 32);
    unsigned char* h2_8   = (unsigned char*)alloc((size_t)nv * 64);
    unsigned int* timg = (unsigned int*)alloc((size_t)VOL * 16 * 2);

    auto blocks = [](long long n) { return (int)((n + 255) / 256); };
    const int nbuckets = (nv + 511) >> 9;
    const int lb = (nv + 127) / 128;  // fused layers: 128 vertices per block

    hipMemsetAsync(bucketCursor, 0, 256 * 4, stream);
    k_transpose<<<VOL / 2 / 256, 256, 0, stream>>>(img, timg);
    k_bucket<<<(ne + EPB - 1) / EPB, 256, 0, stream>>>(esrc, edst, bucketCursor,
                                                       pairs, rowStart, ne, nv);
    k_binsort<<<nbuckets, 256, 0, stream>>>(pairs, bucketCursor, rowStart, invdeg, csrSrc, nv);

    // Features: bf16 rows (MFMA self path) + fp8 rows (gather table)
    k_sample<<<blocks((long long)nv * 2), 256, 0, stream>>>(timg, verts, A, feats8, nv);

    // Layer 0: 19 -> 32 (gather fp8 32B rows; emits h1 bf16 + fp8)
    k_layer_fused<32, 32, true, 19, false, true><<<lb, 256, 0, stream>>>(
        A, feats8, rowStart, csrSrc, invdeg, ws0, wn0, b0, B, h1_8, nv, nullptr, nullptr);

    // Layer 1: 32 -> 64 (gather fp8 32B rows; emits h2 bf16 + fp8)
    k_layer_fused<32, 64, false, 32, false, true><<<lb, 256, 0, stream>>>(
        B, h1_8, rowStart, csrSrc, invdeg, ws1, wn1, b1, A, h2_8, nv, nullptr, nullptr);

    // Layer 2: 64 -> 64 (gather fp8 64B rows; fused premul z = h3 @ Wn3)
    k_layer_fused<64, 64, false, 64, true, false><<<lb, 256, 0, stream>>>(
        A, h2_8, rowStart, csrSrc, invdeg, ws2, wn2, b2, B, nullptr, nv, wn3, Z);

    // Layer 3: fused gather+final update
    k_final<<<blocks(nv), 256, 0, stream>>>(
        B, Z, rowStart, csrSrc, invdeg, ws3, b3, verts, (float*)d_out, nv);
}

// Round 6
// 426.734 us; speedup vs baseline: 1.1655x; 1.1655x over previous
//
#include <hip/hip_runtime.h>

// Problem constants (from reference)
#define C_IMG 16
#define GRIDSZ 128
#define VOL (GRIDSZ * GRIDSZ * GRIDSZ)
#define SLOPE 0.3f
#define SCALE 0.1f
#define EPB 4096         // edges per k_bucket block
#define CAPB 12288       // fixed pair-region capacity per 512-vtx bucket (mean 8192, sd ~90)
#define BIN_CAP 16384    // binsort LDS staging capacity

// btab offsets (bf16 elems): L0 = 32x64, L1 = 64x64, L2 = 64x128
#define BT0_OFF 0
#define BT1_OFF 2048
#define BT2_OFF 6144
#define BT_TOTAL 14336

using f4_t  = __attribute__((ext_vector_type(4))) float;
using bf8_t = __attribute__((ext_vector_type(8))) short;

// bf16 helpers (manual, RNE pack / shift unpack)
__device__ __forceinline__ unsigned int bf16_pack2(float a, float b) {
    unsigned int ua = __float_as_uint(a);
    ua = (ua + 0x7FFFu + ((ua >> 16) & 1u)) >> 16;
    unsigned int ub = __float_as_uint(b);
    ub = (ub + 0x7FFFu + ((ub >> 16) & 1u)) >> 16;
    return ua | (ub << 16);
}
__device__ __forceinline__ unsigned short bf16_1(float a) {
    unsigned int ua = __float_as_uint(a);
    return (unsigned short)((ua + 0x7FFFu + ((ua >> 16) & 1u)) >> 16);
}
__device__ __forceinline__ float bf_lo(unsigned int u) { return __uint_as_float(u << 16); }
__device__ __forceinline__ float bf_hi(unsigned int u) { return __uint_as_float(u & 0xFFFF0000u); }

// ---------------------------------------------------------------------------
// One-time weight prep: build bf16 fragment-ready B tables in GLOBAL memory.
// Layout per layer: bt[c][kk], kk in [0,KTOT): kk<KX -> Ws, else Wn.
// Removes the 17.4KB per-block LDS weight copy from the layer kernels
// (occupancy 4 -> 8 blocks/CU) and the per-block staging loop.
__global__ __launch_bounds__(256) void k_prepw(const float* __restrict__ ws0,
                                               const float* __restrict__ wn0,
                                               const float* __restrict__ ws1,
                                               const float* __restrict__ wn1,
                                               const float* __restrict__ ws2,
                                               const float* __restrict__ wn2,
                                               unsigned short* __restrict__ btab) {
    int i = blockIdx.x * 256 + threadIdx.x;
    if (i < 2048) {                       // L0: COUT=32, KTOT=64, remap, valid 19
        int c = i >> 6, kk = i & 63;
        int j = (kk < 32) ? kk : kk - 32;
        const float* W = (kk < 32) ? ws0 : wn0;
        float w = 0.f;
        if (j < 19) { int sr = (j < 16) ? (j + 3) : (j - 16); w = W[sr * 32 + c]; }
        btab[BT0_OFF + c * 64 + kk] = bf16_1(w);
    } else if (i < 6144) {                // L1: COUT=64, KTOT=64
        int t = i - 2048;
        int c = t >> 6, kk = t & 63;
        int j = (kk < 32) ? kk : kk - 32;
        const float* W = (kk < 32) ? ws1 : wn1;
        btab[BT1_OFF + c * 64 + kk] = bf16_1(W[j * 64 + c]);
    } else if (i < BT_TOTAL) {            // L2: COUT=64, KTOT=128
        int t = i - 6144;
        int c = t >> 7, kk = t & 127;
        int j = (kk < 64) ? kk : kk - 64;
        const float* W = (kk < 64) ? ws2 : wn2;
        btab[BT2_OFF + c * 128 + kk] = bf16_1(W[j * 64 + c]);
    }
}

// ---------------------------------------------------------------------------
// Image transpose: img[16][128][128][128] fp32 -> timg[x][y][z][16] bf16.
__global__ __launch_bounds__(256) void k_transpose(const float* __restrict__ img,
                                                   unsigned int* __restrict__ timg) {
    const int t = blockIdx.x * 256 + threadIdx.x;   // [0, VOL/2)
    const int zp = t & 63;                          // z pair index
    const int xy = t >> 6;                          // x*128+y
    const size_t ibase = (size_t)xy * GRIDSZ + 2 * zp;
    float2 c[16];
    #pragma unroll
    for (int ch = 0; ch < 16; ++ch)
        c[ch] = *(const float2*)(img + (size_t)ch * VOL + ibase);
    uint4 o0a, o0b, o1a, o1b;
    o0a.x = bf16_pack2(c[0].x,  c[1].x);  o0a.y = bf16_pack2(c[2].x,  c[3].x);
    o0a.z = bf16_pack2(c[4].x,  c[5].x);  o0a.w = bf16_pack2(c[6].x,  c[7].x);
    o0b.x = bf16_pack2(c[8].x,  c[9].x);  o0b.y = bf16_pack2(c[10].x, c[11].x);
    o0b.z = bf16_pack2(c[12].x, c[13].x); o0b.w = bf16_pack2(c[14].x, c[15].x);
    o1a.x = bf16_pack2(c[0].y,  c[1].y);  o1a.y = bf16_pack2(c[2].y,  c[3].y);
    o1a.z = bf16_pack2(c[4].y,  c[5].y);  o1a.w = bf16_pack2(c[6].y,  c[7].y);
    o1b.x = bf16_pack2(c[8].y,  c[9].y);  o1b.y = bf16_pack2(c[10].y, c[11].y);
    o1b.z = bf16_pack2(c[12].y, c[13].y); o1b.w = bf16_pack2(c[14].y, c[15].y);
    unsigned int* po = timg + (size_t)(xy * GRIDSZ + 2 * zp) * 8;
    *(uint4*)(po + 0)  = o0a;
    *(uint4*)(po + 4)  = o0b;
    *(uint4*)(po + 8)  = o1a;
    *(uint4*)(po + 12) = o1b;
}

// ---------------------------------------------------------------------------
// Single-pass bucketing into FIXED-CAPACITY per-bucket regions.
// Packed pair: (src<<9)|(dst&511) — src<2^17.
__global__ __launch_bounds__(256) void k_bucket(const int* __restrict__ esrc,
                                                const int* __restrict__ edst,
                                                int* __restrict__ bucketCursor,
                                                unsigned int* __restrict__ pairs,
                                                int* __restrict__ rowStart,
                                                int ne, int nv) {
    __shared__ unsigned int hist[256];
    __shared__ unsigned int pref[256];
    __shared__ unsigned int curs[256];
    __shared__ unsigned int gbase[256];
    __shared__ unsigned int stage_v[EPB];
    __shared__ unsigned char stage_b[EPB];
    const int tid = threadIdx.x;
    const int base = blockIdx.x * EPB;
    const int n = min(EPB, ne - base);
    if (blockIdx.x == 0 && tid == 0) rowStart[nv] = ne;
    hist[tid] = 0;
    __syncthreads();
    for (int i = tid; i < n; i += 256)
        atomicAdd(&hist[((unsigned)edst[base + i]) >> 9], 1u);
    __syncthreads();
    const unsigned int h = hist[tid];
    pref[tid] = h;
    __syncthreads();
    #pragma unroll
    for (int off = 1; off < 256; off <<= 1) {
        unsigned int t = (tid >= off) ? pref[tid - off] : 0;
        __syncthreads();
        pref[tid] += t;
        __syncthreads();
    }
    const unsigned int excl = pref[tid] - h;
    if (h) {
        int pos = atomicAdd(&bucketCursor[tid], (int)h);
        if (pos > CAPB - (int)h) pos = CAPB - (int)h;  // statistically unreachable guard
        gbase[tid] = (unsigned int)(tid * CAPB + pos);
    } else {
        gbase[tid] = 0u;
    }
    __syncthreads();
    pref[tid] = excl;
    curs[tid] = excl;
    __syncthreads();
    for (int i = tid; i < n; i += 256) {
        unsigned int d = (unsigned)edst[base + i];
        unsigned int s = (unsigned)esrc[base + i];
        unsigned int p = atomicAdd(&curs[d >> 9], 1u);
        stage_v[p] = (s << 9) | (d & 511u);
        stage_b[p] = (unsigned char)(d >> 9);
    }
    __syncthreads();
    for (int i = tid; i < n; i += 256) {
        unsigned int b = stage_b[i];
        pairs[gbase[b] + (unsigned)i - pref[b]] = stage_v[i];
    }
}

// Within-bucket sort -> dense csrSrc + rowStart + invdeg.
__global__ __launch_bounds__(256) void k_binsort(const unsigned int* __restrict__ pairs,
                                                 const int* __restrict__ bucketCursor,
                                                 int* __restrict__ rowStart,
                                                 float* __restrict__ invdeg,
                                                 int* __restrict__ csrSrc, int nv) {
    __shared__ int deg_s[512];
    __shared__ int rs_s[512];
    __shared__ int cur_s[512];
    __shared__ int scan_s[256];
    __shared__ int bb[256];
    __shared__ int outbuf[BIN_CAP];
    const int tid = threadIdx.x;
    const int b = blockIdx.x;
    const int vbase = b << 9;
    if (vbase >= nv) return;
    const int nvb = min(512, nv - vbase);
    const int c = min(bucketCursor[tid], CAPB);
    bb[tid] = c;
    deg_s[tid] = 0;
    deg_s[tid + 256] = 0;
    __syncthreads();
    #pragma unroll
    for (int off = 1; off < 256; off <<= 1) {
        int t = (tid >= off) ? bb[tid - off] : 0;
        __syncthreads();
        bb[tid] += t;
        __syncthreads();
    }
    const int count = min(bucketCursor[b], CAPB);
    const int gs = bb[b] - count;
    const unsigned int* pbase = pairs + (size_t)b * CAPB;
    for (int i = tid; i < count; i += 256) {
        unsigned int p = pbase[i];
        atomicAdd(&deg_s[p & 511u], 1);
    }
    __syncthreads();
    const int d0 = deg_s[2 * tid];
    const int d1 = deg_s[2 * tid + 1];
    const int ps = d0 + d1;
    scan_s[tid] = ps;
    __syncthreads();
    #pragma unroll
    for (int off = 1; off < 256; off <<= 1) {
        int t = (tid >= off) ? scan_s[tid - off] : 0;
        __syncthreads();
        scan_s[tid] += t;
        __syncthreads();
    }
    const int epair = scan_s[tid] - ps;
    rs_s[2 * tid] = epair;
    rs_s[2 * tid + 1] = epair + d0;
    cur_s[2 * tid] = epair;
    cur_s[2 * tid + 1] = epair + d0;
    #pragma unroll
    for (int u = 0; u < 2; ++u) {
        int idx = 2 * tid + u;
        if (idx < nvb) {
            rowStart[vbase + idx] = gs + rs_s[idx];
            int d = deg_s[idx];
            invdeg[vbase + idx] = 1.0f / (float)(d > 1 ? d : 1);
        }
    }
    __syncthreads();
    for (int i = tid; i < count; i += 256) {
        unsigned int p = pbase[i];
        int pos = atomicAdd(&cur_s[p & 511u], 1);
        outbuf[pos] = (int)(p >> 9);
    }
    __syncthreads();
    for (int i = tid; i < count; i += 256) csrSrc[gs + i] = outbuf[i];
}

// ---------------------------------------------------------------------------
// Trilinear sample -> bf16 feats rows, stride 16 uints (32 bf16 cols):
// cols 0..15 = channels, 16..18 = verts/128, 19..31 = 0.
__global__ __launch_bounds__(256) void k_sample(const unsigned int* __restrict__ timg,
                                                const float* __restrict__ verts,
                                                unsigned int* __restrict__ feats, int nv) {
    int t = blockIdx.x * 256 + threadIdx.x;
    int v = t >> 1;
    int q = t & 1;          // channel group: q*8 .. q*8+7
    if (v >= nv) return;
    float px = verts[v * 3 + 0];
    float py = verts[v * 3 + 1];
    float pz = verts[v * 3 + 2];
    float cx = fminf(fmaxf(px, 0.0f), 127.0f);
    float cy = fminf(fmaxf(py, 0.0f), 127.0f);
    float cz = fminf(fmaxf(pz, 0.0f), 127.0f);
    float fx = floorf(cx), fy = floorf(cy), fz = floorf(cz);
    int x0 = (int)fx, y0 = (int)fy, z0 = (int)fz;
    int x1 = min(x0 + 1, 127), y1 = min(y0 + 1, 127), z1 = min(z0 + 1, 127);
    float wx = cx - fx, wy = cy - fy, wz = cz - fz;
    const int qo = q * 4;
    #define LD(X, Y, Z) (*(const uint4*)(timg + ((size_t)((((X) << 7) + (Y)) << 7) + (size_t)(Z)) * 8 + qo))
    uint4 f000 = LD(x0, y0, z0), f001 = LD(x0, y0, z1);
    uint4 f010 = LD(x0, y1, z0), f011 = LD(x0, y1, z1);
    uint4 f100 = LD(x1, y0, z0), f101 = LD(x1, y0, z1);
    uint4 f110 = LD(x1, y1, z0), f111 = LD(x1, y1, z1);
    #undef LD
    float r[8];
    const unsigned int* a000 = (const unsigned int*)&f000;
    const unsigned int* a001 = (const unsigned int*)&f001;
    const unsigned int* a010 = (const unsigned int*)&f010;
    const unsigned int* a011 = (const unsigned int*)&f011;
    const unsigned int* a100 = (const unsigned int*)&f100;
    const unsigned int* a101 = (const unsigned int*)&f101;
    const unsigned int* a110 = (const unsigned int*)&f110;
    const unsigned int* a111 = (const unsigned int*)&f111;
    #pragma unroll
    for (int u = 0; u < 4; ++u) {
        float c00l = bf_lo(a000[u]) * (1.f - wz) + bf_lo(a001[u]) * wz;
        float c01l = bf_lo(a010[u]) * (1.f - wz) + bf_lo(a011[u]) * wz;
        float c10l = bf_lo(a100[u]) * (1.f - wz) + bf_lo(a101[u]) * wz;
        float c11l = bf_lo(a110[u]) * (1.f - wz) + bf_lo(a111[u]) * wz;
        r[2 * u] = (c00l * (1.f - wy) + c01l * wy) * (1.f - wx) +
                   (c10l * (1.f - wy) + c11l * wy) * wx;
        float c00h = bf_hi(a000[u]) * (1.f - wz) + bf_hi(a001[u]) * wz;
        float c01h = bf_hi(a010[u]) * (1.f - wz) + bf_hi(a011[u]) * wz;
        float c10h = bf_hi(a100[u]) * (1.f - wz) + bf_hi(a101[u]) * wz;
        float c11h = bf_hi(a110[u]) * (1.f - wz) + bf_hi(a111[u]) * wz;
        r[2 * u + 1] = (c00h * (1.f - wy) + c01h * wy) * (1.f - wx) +
                       (c10h * (1.f - wy) + c11h * wy) * wx;
    }
    unsigned int* row = feats + (size_t)v * 16;
    uint4 o;
    o.x = bf16_pack2(r[0], r[1]); o.y = bf16_pack2(r[2], r[3]);
    o.z = bf16_pack2(r[4], r[5]); o.w = bf16_pack2(r[6], r[7]);
    *(uint4*)(row + q * 4) = o;
    if (q == 0) {
        uint4 o2;
        o2.x = bf16_pack2(px * (1.0f / 128.0f), py * (1.0f / 128.0f));
        o2.y = bf16_pack2(pz * (1.0f / 128.0f), 0.0f);
        o2.z = 0u; o2.w = 0u;
        *(uint4*)(row + 8) = o2;
        *(uint4*)(row + 12) = make_uint4(0u, 0u, 0u, 0u);
    }
}

// ---------------------------------------------------------------------------
// FUSED gather + MFMA edge-conv (bf16 gather; B-fragments from GLOBAL btab).
//   nb_s[vloc][*] = bf16( invdeg[v] * sum_{s in N(v)} x[s][*] )   (LDS tile)
//   out = leakyrelu([x | nb] @ [[Ws],[Wn]] + b)
// LDS = nb_s only (10.2/18.4 KB) -> 8 blocks/CU for latency hiding.
// A frag: lane row = l&15, 8 contiguous k at (l>>4)*8 (16B load).
// B frag: global load from fragment-ready btab (L2-hot 28.7KB table).
// D: col = lane&15, row = (lane>>4)*4 + reg  [m89-verified mapping].
// PREMUL (layer 2): emit z = act(h3) @ Wn3 via 16-lane shfl reduce.
template <int KX, int COUT, bool PREMUL>
__global__ __launch_bounds__(256) void k_layer_fused(const unsigned int* __restrict__ x,
                                                     const unsigned short* __restrict__ btab,
                                                     const int* __restrict__ rowStart,
                                                     const int* __restrict__ csrSrc,
                                                     const float* __restrict__ invdeg,
                                                     const float* __restrict__ bias,
                                                     unsigned int* __restrict__ out, int nv,
                                                     const float* __restrict__ Wn3,
                                                     unsigned int* __restrict__ zout) {
    constexpr int KTOT = 2 * KX;
    constexpr int NT = COUT / 16;     // n-tiles per wave
    constexpr int MT = 2;             // m-tiles per wave (32 vertices)
    constexpr int SXU = KX / 2;       // x row stride in uints
    constexpr int KS = KX / 32;       // k-steps per source
    constexpr int VPB = 128;          // vertices per block
    constexpr int NCH = KX / 8;       // 16B chunks per gathered row
    constexpr int NBW = KX + 8;       // nb_s row stride (bf16); stride/4 mod 32 = 2-way (free)
    __shared__ __align__(16) unsigned short nb_s[VPB * NBW];

    // Gather phase: accumulate neighbor rows in registers, write bf16 to LDS.
    const int vb0 = blockIdx.x * VPB;
    for (int task = threadIdx.x; task < VPB * NCH; task += 256) {
        const int vloc = task / NCH;
        const int ch = task - vloc * NCH;
        const int v = vb0 + vloc;
        unsigned short* dst = nb_s + vloc * NBW + ch * 8;
        if (v < nv) {
            int beg = rowStart[v];
            int end = rowStart[v + 1];
            float a0 = 0.f, a1 = 0.f, a2 = 0.f, a3 = 0.f,
                  a4 = 0.f, a5 = 0.f, a6 = 0.f, a7 = 0.f;
            int j = beg;
            for (; j + 3 < end; j += 4) {
                int s0 = csrSrc[j];
                int s1 = csrSrc[j + 1];
                int s2 = csrSrc[j + 2];
                int s3 = csrSrc[j + 3];
                uint4 q0 = ((const uint4*)(x + (size_t)s0 * SXU))[ch];
                uint4 q1 = ((const uint4*)(x + (size_t)s1 * SXU))[ch];
                uint4 q2 = ((const uint4*)(x + (size_t)s2 * SXU))[ch];
                uint4 q3 = ((const uint4*)(x + (size_t)s3 * SXU))[ch];
                a0 += bf_lo(q0.x); a1 += bf_hi(q0.x);
                a2 += bf_lo(q0.y); a3 += bf_hi(q0.y);
                a4 += bf_lo(q0.z); a5 += bf_hi(q0.z);
                a6 += bf_lo(q0.w); a7 += bf_hi(q0.w);
                a0 += bf_lo(q1.x); a1 += bf_hi(q1.x);
                a2 += bf_lo(q1.y); a3 += bf_hi(q1.y);
                a4 += bf_lo(q1.z); a5 += bf_hi(q1.z);
                a6 += bf_lo(q1.w); a7 += bf_hi(q1.w);
                a0 += bf_lo(q2.x); a1 += bf_hi(q2.x);
                a2 += bf_lo(q2.y); a3 += bf_hi(q2.y);
                a4 += bf_lo(q2.z); a5 += bf_hi(q2.z);
                a6 += bf_lo(q2.w); a7 += bf_hi(q2.w);
                a0 += bf_lo(q3.x); a1 += bf_hi(q3.x);
                a2 += bf_lo(q3.y); a3 += bf_hi(q3.y);
                a4 += bf_lo(q3.z); a5 += bf_hi(q3.z);
                a6 += bf_lo(q3.w); a7 += bf_hi(q3.w);
            }
            for (; j < end; ++j) {
                int s = csrSrc[j];
                uint4 q = ((const uint4*)(x + (size_t)s * SXU))[ch];
                a0 += bf_lo(q.x); a1 += bf_hi(q.x);
                a2 += bf_lo(q.y); a3 += bf_hi(q.y);
                a4 += bf_lo(q.z); a5 += bf_hi(q.z);
                a6 += bf_lo(q.w); a7 += bf_hi(q.w);
            }
            const float id = invdeg[v];
            uint4 o;
            o.x = bf16_pack2(a0 * id, a1 * id); o.y = bf16_pack2(a2 * id, a3 * id);
            o.z = bf16_pack2(a4 * id, a5 * id); o.w = bf16_pack2(a6 * id, a7 * id);
            *(uint4*)dst = o;
        } else {
            *(uint4*)dst = make_uint4(0u, 0u, 0u, 0u);
        }
    }
    __syncthreads();

    const int lane = threadIdx.x & 63;
    const int wid = threadIdx.x >> 6;
    const int v0 = vb0 + wid * (MT * 16);
    const int row = lane & 15;
    const int kg = lane >> 4;         // k-subgroup: 8 contiguous k at kg*8

    f4_t acc[MT][NT] = {};

    #pragma unroll
    for (int ks = 0; ks < 2 * KS; ++ks) {
        bf8_t afrag[MT];
        if (ks < KS) {
            const int kbase = ks * 32;
            #pragma unroll
            for (int mt = 0; mt < MT; ++mt) {
                int v = v0 + mt * 16 + row;
                v = min(v, nv - 1);   // clamp: duplicate row, masked at store
                afrag[mt] = *(const bf8_t*)(x + (size_t)v * SXU + ((kbase + kg * 8) >> 1));
            }
        } else {
            const int kbase = (ks - KS) * 32;
            #pragma unroll
            for (int mt = 0; mt < MT; ++mt) {
                const int vloc = wid * (MT * 16) + mt * 16 + row;
                afrag[mt] = *(const bf8_t*)(nb_s + vloc * NBW + kbase + kg * 8);
            }
        }
        #pragma unroll
        for (int nt = 0; nt < NT; ++nt) {
            bf8_t bfrag = *(const bf8_t*)(btab + (nt * 16 + row) * KTOT + ks * 32 + kg * 8);
            #pragma unroll
            for (int mt = 0; mt < MT; ++mt)
                acc[mt][nt] = __builtin_amdgcn_mfma_f32_16x16x32_bf16(afrag[mt], bfrag,
                                                                      acc[mt][nt], 0, 0, 0);
        }
    }

    // Epilogue: bias + leaky relu, bf16 2B stores; optional fused premul.
    unsigned short* po = (unsigned short*)out;
    float bq[NT];
    #pragma unroll
    for (int nt = 0; nt < NT; ++nt) bq[nt] = bias[nt * 16 + row];
    float wz[PREMUL ? NT : 1][3];
    if constexpr (PREMUL) {
        #pragma unroll
        for (int nt = 0; nt < NT; ++nt) {
            const float* wr = Wn3 + (nt * 16 + row) * 3;
            wz[nt][0] = wr[0]; wz[nt][1] = wr[1]; wz[nt][2] = wr[2];
        }
    }
    #pragma unroll
    for (int mt = 0; mt < MT; ++mt) {
        #pragma unroll
        for (int r = 0; r < 4; ++r) {
            const int v = v0 + mt * 16 + kg * 4 + r;
            float tv[NT];
            #pragma unroll
            for (int nt = 0; nt < NT; ++nt) {
                float t = acc[mt][nt][r] + bq[nt];
                t = (t >= 0.f) ? t : SLOPE * t;
                tv[nt] = t;
                if (v < nv) po[(size_t)v * COUT + nt * 16 + row] = bf16_1(t);
            }
            if constexpr (PREMUL) {
                float z0 = 0.f, z1 = 0.f, z2 = 0.f;
                #pragma unroll
                for (int nt = 0; nt < NT; ++nt) {
                    z0 += tv[nt] * wz[nt][0];
                    z1 += tv[nt] * wz[nt][1];
                    z2 += tv[nt] * wz[nt][2];
                }
                #pragma unroll
                for (int m = 1; m < 16; m <<= 1) {
                    z0 += __shfl_xor(z0, m);
                    z1 += __shfl_xor(z1, m);
                    z2 += __shfl_xor(z2, m);
                }
                if (row == 0 && v < nv) {
                    uint2 o;
                    o.x = bf16_pack2(z0, z1);
                    o.y = bf16_pack2(z2, 0.f);
                    *(uint2*)(zout + (size_t)v * 2) = o;
                }
            }
        }
    }
}

// Final (fused z-gather): out = verts + SCALE*(h3@Ws3 + gather(z)*inv_deg + b3)
__global__ __launch_bounds__(256) void k_final(const unsigned int* __restrict__ h,
                                               const unsigned int* __restrict__ z,
                                               const int* __restrict__ rowStart,
                                               const int* __restrict__ csrSrc,
                                               const float* __restrict__ invdeg,
                                               const float* __restrict__ ws,
                                               const float* __restrict__ b,
                                               const float* __restrict__ verts,
                                               float* __restrict__ out, int nv) {
    __shared__ float w_s[64 * 3];
    if (threadIdx.x < 64 * 3) w_s[threadIdx.x] = ws[threadIdx.x];
    __syncthreads();
    int v = blockIdx.x * 256 + threadIdx.x;
    if (v >= nv) return;
    float n0 = 0.f, n1 = 0.f, n2 = 0.f;
    {
        int beg = rowStart[v];
        int end = rowStart[v + 1];
        int j = beg;
        for (; j + 3 < end; j += 4) {
            int s0 = csrSrc[j];
            int s1 = csrSrc[j + 1];
            int s2 = csrSrc[j + 2];
            int s3 = csrSrc[j + 3];
            uint2 q0 = *(const uint2*)(z + (size_t)s0 * 2);
            uint2 q1 = *(const uint2*)(z + (size_t)s1 * 2);
            uint2 q2 = *(const uint2*)(z + (size_t)s2 * 2);
            uint2 q3 = *(const uint2*)(z + (size_t)s3 * 2);
            n0 += bf_lo(q0.x); n1 += bf_hi(q0.x); n2 += bf_lo(q0.y);
            n0 += bf_lo(q1.x); n1 += bf_hi(q1.x); n2 += bf_lo(q1.y);
            n0 += bf_lo(q2.x); n1 += bf_hi(q2.x); n2 += bf_lo(q2.y);
            n0 += bf_lo(q3.x); n1 += bf_hi(q3.x); n2 += bf_lo(q3.y);
        }
        for (; j < end; ++j) {
            int s = csrSrc[j];
            uint2 q = *(const uint2*)(z + (size_t)s * 2);
            n0 += bf_lo(q.x); n1 += bf_hi(q.x); n2 += bf_lo(q.y);
        }
    }
    const uint4* hr = (const uint4*)(h + (size_t)v * 32);
    float a0 = b[0], a1 = b[1], a2 = b[2];
    #pragma unroll
    for (int q = 0; q < 8; ++q) {
        uint4 hv = hr[q];
        float f[8] = {bf_lo(hv.x), bf_hi(hv.x), bf_lo(hv.y), bf_hi(hv.y),
                      bf_lo(hv.z), bf_hi(hv.z), bf_lo(hv.w), bf_hi(hv.w)};
        #pragma unroll
        for (int i = 0; i < 8; ++i) {
            int k = q * 8 + i;
            a0 += f[i] * w_s[k * 3 + 0];
            a1 += f[i] * w_s[k * 3 + 1];
            a2 += f[i] * w_s[k * 3 + 2];
        }
    }
    float id = invdeg[v];
    a0 += n0 * id; a1 += n1 * id; a2 += n2 * id;
    out[(size_t)v * 3 + 0] = verts[(size_t)v * 3 + 0] + SCALE * a0;
    out[(size_t)v * 3 + 1] = verts[(size_t)v * 3 + 1] + SCALE * a1;
    out[(size_t)v * 3 + 2] = verts[(size_t)v * 3 + 2] + SCALE * a2;
}

// ---------------------------------------------------------------------------
extern "C" void kernel_launch(void* const* d_in, const int* in_sizes, int n_in,
                              void* d_out, int out_size, void* d_ws, size_t ws_size,
                              hipStream_t stream) {
    const float* img   = (const float*)d_in[0];
    const float* verts = (const float*)d_in[1];
    const int*   esrc  = (const int*)d_in[2];
    const int*   edst  = (const int*)d_in[3];
    const float* ws0 = (const float*)d_in[4];
    const float* wn0 = (const float*)d_in[5];
    const float* b0  = (const float*)d_in[6];
    const float* ws1 = (const float*)d_in[7];
    const float* wn1 = (const float*)d_in[8];
    const float* b1  = (const float*)d_in[9];
    const float* ws2 = (const float*)d_in[10];
    const float* wn2 = (const float*)d_in[11];
    const float* b2  = (const float*)d_in[12];
    const float* ws3 = (const float*)d_in[13];
    const float* wn3 = (const float*)d_in[14];
    const float* b3  = (const float*)d_in[15];

    const int nv = in_sizes[1] / 3;
    const int ne = in_sizes[2];

    char* base = (char*)d_ws;
    size_t off = 0;
    auto alloc = [&](size_t bytes) -> void* {
        off = (off + 255) & ~(size_t)255;
        void* p = base + off;
        off += bytes;
        return p;
    };
    float* invdeg   = (float*)alloc((size_t)nv * 4);
    int*   rowStart = (int*)alloc((size_t)(nv + 1) * 4);
    int*   bucketCursor = (int*)alloc(256 * 4);
    int*   csrSrc   = (int*)alloc((size_t)ne * 4);
    unsigned int* pairs = (unsigned int*)alloc((size_t)256 * CAPB * 4);
    unsigned int* A   = (unsigned int*)alloc((size_t)nv * 32 * 4);  // feats(16u) then h2(32u)
    unsigned int* B   = (unsigned int*)alloc((size_t)nv * 32 * 4);  // h1(16u) then h3(32u)
    unsigned int* Z   = (unsigned int*)alloc((size_t)nv * 2 * 4);   // bf16 premultiplied
    unsigned short* btab = (unsigned short*)alloc(BT_TOTAL * 2);    // fragment-ready weights
    unsigned int* timg = (unsigned int*)alloc((size_t)VOL * 16 * 2);

    auto blocks = [](long long n) { return (int)((n + 255) / 256); };
    const int nbuckets = (nv + 511) >> 9;
    const int lb = (nv + 127) / 128;  // fused layers: 128 vertices per block

    hipMemsetAsync(bucketCursor, 0, 256 * 4, stream);
    k_prepw<<<(BT_TOTAL + 255) / 256, 256, 0, stream>>>(ws0, wn0, ws1, wn1, ws2, wn2, btab);
    k_transpose<<<VOL / 2 / 256, 256, 0, stream>>>(img, timg);
    k_bucket<<<(ne + EPB - 1) / EPB, 256, 0, stream>>>(esrc, edst, bucketCursor,
                                                       pairs, rowStart, ne, nv);
    k_binsort<<<nbuckets, 256, 0, stream>>>(pairs, bucketCursor, rowStart, invdeg, csrSrc, nv);

    // Features (channel-last bf16 volume) -> bf16 feats
    k_sample<<<blocks((long long)nv * 2), 256, 0, stream>>>(timg, verts, A, nv);

    // Layer 0: 19 -> 32 (feats stride 16u, KX=32)
    k_layer_fused<32, 32, false><<<lb, 256, 0, stream>>>(
        A, btab + BT0_OFF, rowStart, csrSrc, invdeg, b0, B, nv, nullptr, nullptr);

    // Layer 1: 32 -> 64 (h1 stride 16u, KX=32)
    k_layer_fused<32, 64, false><<<lb, 256, 0, stream>>>(
        B, btab + BT1_OFF, rowStart, csrSrc, invdeg, b1, A, nv, nullptr, nullptr);

    // Layer 2: 64 -> 64 (h2 stride 32u, KX=64), fused premul z = h3 @ Wn3
    k_layer_fused<64, 64, true><<<lb, 256, 0, stream>>>(
        A, btab + BT2_OFF, rowStart, csrSrc, invdeg, b2, B, nv, wn3, Z);

    // Layer 3: fused gather+final update
    k_final<<<blocks(nv), 256, 0, stream>>>(
        B, Z, rowStart, csrSrc, invdeg, ws3, b3, verts, (float*)d_out, nv);
}

// Round 7
// 416.354 us; speedup vs baseline: 1.1946x; 1.0249x over previous
//
#include <hip/hip_runtime.h>

// Problem constants (from reference)
#define C_IMG 16
#define GRIDSZ 128
#define VOL (GRIDSZ * GRIDSZ * GRIDSZ)
#define SLOPE 0.3f
#define SCALE 0.1f
#define EPB 4096         // edges per k_bucket block
#define CAPB 12288       // fixed pair-region capacity per 512-vtx bucket (mean 8192, sd ~90)
#define BIN_CAP 16384    // binsort LDS staging capacity

// btab offsets (bf16 elems): L0 = 32x64, L1 = 64x64, L2 = 64x128
#define BT0_OFF 0
#define BT1_OFF 2048
#define BT2_OFF 6144
#define BT_TOTAL 14336

using f4_t  = __attribute__((ext_vector_type(4))) float;
using bf8_t = __attribute__((ext_vector_type(8))) short;

// bf16 helpers (manual, RNE pack / shift unpack)
__device__ __forceinline__ unsigned int bf16_pack2(float a, float b) {
    unsigned int ua = __float_as_uint(a);
    ua = (ua + 0x7FFFu + ((ua >> 16) & 1u)) >> 16;
    unsigned int ub = __float_as_uint(b);
    ub = (ub + 0x7FFFu + ((ub >> 16) & 1u)) >> 16;
    return ua | (ub << 16);
}
__device__ __forceinline__ unsigned short bf16_1(float a) {
    unsigned int ua = __float_as_uint(a);
    return (unsigned short)((ua + 0x7FFFu + ((ua >> 16) & 1u)) >> 16);
}
__device__ __forceinline__ float bf_lo(unsigned int u) { return __uint_as_float(u << 16); }
__device__ __forceinline__ float bf_hi(unsigned int u) { return __uint_as_float(u & 0xFFFF0000u); }

// ---------------------------------------------------------------------------
// One-time weight prep: build bf16 fragment-ready B tables in GLOBAL memory.
__global__ __launch_bounds__(256) void k_prepw(const float* __restrict__ ws0,
                                               const float* __restrict__ wn0,
                                               const float* __restrict__ ws1,
                                               const float* __restrict__ wn1,
                                               const float* __restrict__ ws2,
                                               const float* __restrict__ wn2,
                                               unsigned short* __restrict__ btab) {
    int i = blockIdx.x * 256 + threadIdx.x;
    if (i < 2048) {                       // L0: COUT=32, KTOT=64, remap, valid 19
        int c = i >> 6, kk = i & 63;
        int j = (kk < 32) ? kk : kk - 32;
        const float* W = (kk < 32) ? ws0 : wn0;
        float w = 0.f;
        if (j < 19) { int sr = (j < 16) ? (j + 3) : (j - 16); w = W[sr * 32 + c]; }
        btab[BT0_OFF + c * 64 + kk] = bf16_1(w);
    } else if (i < 6144) {                // L1: COUT=64, KTOT=64
        int t = i - 2048;
        int c = t >> 6, kk = t & 63;
        int j = (kk < 32) ? kk : kk - 32;
        const float* W = (kk < 32) ? ws1 : wn1;
        btab[BT1_OFF + c * 64 + kk] = bf16_1(W[j * 64 + c]);
    } else if (i < BT_TOTAL) {            // L2: COUT=64, KTOT=128
        int t = i - 6144;
        int c = t >> 7, kk = t & 127;
        int j = (kk < 64) ? kk : kk - 64;
        const float* W = (kk < 64) ? ws2 : wn2;
        btab[BT2_OFF + c * 128 + kk] = bf16_1(W[j * 64 + c]);
    }
}

// ---------------------------------------------------------------------------
// Image transpose: img[16][128][128][128] fp32 -> timg[x][y][z][16] bf16.
// One thread = one 16B output chunk (8 channels of one z): 8 INDEPENDENT 4B
// loads (per wave: 32 consecutive z per channel segment = coalesced 128B),
// ~8 VGPRs of live data so the compiler keeps all loads in flight (the R5
// version needed 32 VGPRs for c[16] and got serialized into a latency chain
// at 1.65 TB/s). Writes: 16B/lane, wave-contiguous 1KB.
__global__ __launch_bounds__(256) void k_transpose(const float* __restrict__ img,
                                                   unsigned int* __restrict__ timg) {
    const int tid = threadIdx.x;
    const int xy = blockIdx.x;                 // x*128+y
    const int zlo = tid & 31;
    const int half = (tid >> 5) & 1;           // channel half: 0 -> ch0..7, 1 -> ch8..15
    const int zhi = tid >> 6;                  // 0..3
    const int z = zhi * 32 + zlo;
    const size_t ib = (size_t)xy * GRIDSZ + z;
    const int c0 = half * 8;
    float f[8];
    #pragma unroll
    for (int c = 0; c < 8; ++c)
        f[c] = img[(size_t)(c0 + c) * VOL + ib];
    uint4 o;
    o.x = bf16_pack2(f[0], f[1]);
    o.y = bf16_pack2(f[2], f[3]);
    o.z = bf16_pack2(f[4], f[5]);
    o.w = bf16_pack2(f[6], f[7]);
    *(uint4*)(timg + ((size_t)xy * GRIDSZ + z) * 8 + half * 4) = o;
}

// ---------------------------------------------------------------------------
// Single-pass bucketing into FIXED-CAPACITY per-bucket regions.
// Packed pair: (src<<9)|(dst&511) — src<2^17.
__global__ __launch_bounds__(256) void k_bucket(const int* __restrict__ esrc,
                                                const int* __restrict__ edst,
                                                int* __restrict__ bucketCursor,
                                                unsigned int* __restrict__ pairs,
                                                int* __restrict__ rowStart,
                                                int ne, int nv) {
    __shared__ unsigned int hist[256];
    __shared__ unsigned int pref[256];
    __shared__ unsigned int curs[256];
    __shared__ unsigned int gbase[256];
    __shared__ unsigned int stage_v[EPB];
    __shared__ unsigned char stage_b[EPB];
    const int tid = threadIdx.x;
    const int base = blockIdx.x * EPB;
    const int n = min(EPB, ne - base);
    if (blockIdx.x == 0 && tid == 0) rowStart[nv] = ne;
    hist[tid] = 0;
    __syncthreads();
    for (int i = tid; i < n; i += 256)
        atomicAdd(&hist[((unsigned)edst[base + i]) >> 9], 1u);
    __syncthreads();
    const unsigned int h = hist[tid];
    pref[tid] = h;
    __syncthreads();
    #pragma unroll
    for (int off = 1; off < 256; off <<= 1) {
        unsigned int t = (tid >= off) ? pref[tid - off] : 0;
        __syncthreads();
        pref[tid] += t;
        __syncthreads();
    }
    const unsigned int excl = pref[tid] - h;
    if (h) {
        int pos = atomicAdd(&bucketCursor[tid], (int)h);
        if (pos > CAPB - (int)h) pos = CAPB - (int)h;  // statistically unreachable guard
        gbase[tid] = (unsigned int)(tid * CAPB + pos);
    } else {
        gbase[tid] = 0u;
    }
    __syncthreads();
    pref[tid] = excl;
    curs[tid] = excl;
    __syncthreads();
    for (int i = tid; i < n; i += 256) {
        unsigned int d = (unsigned)edst[base + i];
        unsigned int s = (unsigned)esrc[base + i];
        unsigned int p = atomicAdd(&curs[d >> 9], 1u);
        stage_v[p] = (s << 9) | (d & 511u);
        stage_b[p] = (unsigned char)(d >> 9);
    }
    __syncthreads();
    for (int i = tid; i < n; i += 256) {
        unsigned int b = stage_b[i];
        pairs[gbase[b] + (unsigned)i - pref[b]] = stage_v[i];
    }
}

// Within-bucket sort -> dense csrSrc + rowStart + invdeg.
__global__ __launch_bounds__(256) void k_binsort(const unsigned int* __restrict__ pairs,
                                                 const int* __restrict__ bucketCursor,
                                                 int* __restrict__ rowStart,
                                                 float* __restrict__ invdeg,
                                                 int* __restrict__ csrSrc, int nv) {
    __shared__ int deg_s[512];
    __shared__ int rs_s[512];
    __shared__ int cur_s[512];
    __shared__ int scan_s[256];
    __shared__ int bb[256];
    __shared__ int outbuf[BIN_CAP];
    const int tid = threadIdx.x;
    const int b = blockIdx.x;
    const int vbase = b << 9;
    if (vbase >= nv) return;
    const int nvb = min(512, nv - vbase);
    const int c = min(bucketCursor[tid], CAPB);
    bb[tid] = c;
    deg_s[tid] = 0;
    deg_s[tid + 256] = 0;
    __syncthreads();
    #pragma unroll
    for (int off = 1; off < 256; off <<= 1) {
        int t = (tid >= off) ? bb[tid - off] : 0;
        __syncthreads();
        bb[tid] += t;
        __syncthreads();
    }
    const int count = min(bucketCursor[b], CAPB);
    const int gs = bb[b] - count;
    const unsigned int* pbase = pairs + (size_t)b * CAPB;
    for (int i = tid; i < count; i += 256) {
        unsigned int p = pbase[i];
        atomicAdd(&deg_s[p & 511u], 1);
    }
    __syncthreads();
    const int d0 = deg_s[2 * tid];
    const int d1 = deg_s[2 * tid + 1];
    const int ps = d0 + d1;
    scan_s[tid] = ps;
    __syncthreads();
    #pragma unroll
    for (int off = 1; off < 256; off <<= 1) {
        int t = (tid >= off) ? scan_s[tid - off] : 0;
        __syncthreads();
        scan_s[tid] += t;
        __syncthreads();
    }
    const int epair = scan_s[tid] - ps;
    rs_s[2 * tid] = epair;
    rs_s[2 * tid + 1] = epair + d0;
    cur_s[2 * tid] = epair;
    cur_s[2 * tid + 1] = epair + d0;
    #pragma unroll
    for (int u = 0; u < 2; ++u) {
        int idx = 2 * tid + u;
        if (idx < nvb) {
            rowStart[vbase + idx] = gs + rs_s[idx];
            int d = deg_s[idx];
            invdeg[vbase + idx] = 1.0f / (float)(d > 1 ? d : 1);
        }
    }
    __syncthreads();
    for (int i = tid; i < count; i += 256) {
        unsigned int p = pbase[i];
        int pos = atomicAdd(&cur_s[p & 511u], 1);
        outbuf[pos] = (int)(p >> 9);
    }
    __syncthreads();
    for (int i = tid; i < count; i += 256) csrSrc[gs + i] = outbuf[i];
}

// ---------------------------------------------------------------------------
// Trilinear sample -> bf16 feats rows, stride 16 uints (32 bf16 cols):
// cols 0..15 = channels, 16..18 = verts/128, 19..31 = 0.
__global__ __launch_bounds__(256) void k_sample(const unsigned int* __restrict__ timg,
                                                const float* __restrict__ verts,
                                                unsigned int* __restrict__ feats, int nv) {
    int t = blockIdx.x * 256 + threadIdx.x;
    int v = t >> 1;
    int q = t & 1;          // channel group: q*8 .. q*8+7
    if (v >= nv) return;
    float px = verts[v * 3 + 0];
    float py = verts[v * 3 + 1];
    float pz = verts[v * 3 + 2];
    float cx = fminf(fmaxf(px, 0.0f), 127.0f);
    float cy = fminf(fmaxf(py, 0.0f), 127.0f);
    float cz = fminf(fmaxf(pz, 0.0f), 127.0f);
    float fx = floorf(cx), fy = floorf(cy), fz = floorf(cz);
    int x0 = (int)fx, y0 = (int)fy, z0 = (int)fz;
    int x1 = min(x0 + 1, 127), y1 = min(y0 + 1, 127), z1 = min(z0 + 1, 127);
    float wx = cx - fx, wy = cy - fy, wz = cz - fz;
    const int qo = q * 4;
    #define LD(X, Y, Z) (*(const uint4*)(timg + ((size_t)((((X) << 7) + (Y)) << 7) + (size_t)(Z)) * 8 + qo))
    uint4 f000 = LD(x0, y0, z0), f001 = LD(x0, y0, z1);
    uint4 f010 = LD(x0, y1, z0), f011 = LD(x0, y1, z1);
    uint4 f100 = LD(x1, y0, z0), f101 = LD(x1, y0, z1);
    uint4 f110 = LD(x1, y1, z0), f111 = LD(x1, y1, z1);
    #undef LD
    float r[8];
    const unsigned int* a000 = (const unsigned int*)&f000;
    const unsigned int* a001 = (const unsigned int*)&f001;
    const unsigned int* a010 = (const unsigned int*)&f010;
    const unsigned int* a011 = (const unsigned int*)&f011;
    const unsigned int* a100 = (const unsigned int*)&f100;
    const unsigned int* a101 = (const unsigned int*)&f101;
    const unsigned int* a110 = (const unsigned int*)&f110;
    const unsigned int* a111 = (const unsigned int*)&f111;
    #pragma unroll
    for (int u = 0; u < 4; ++u) {
        float c00l = bf_lo(a000[u]) * (1.f - wz) + bf_lo(a001[u]) * wz;
        float c01l = bf_lo(a010[u]) * (1.f - wz) + bf_lo(a011[u]) * wz;
        float c10l = bf_lo(a100[u]) * (1.f - wz) + bf_lo(a101[u]) * wz;
        float c11l = bf_lo(a110[u]) * (1.f - wz) + bf_lo(a111[u]) * wz;
        r[2 * u] = (c00l * (1.f - wy) + c01l * wy) * (1.f - wx) +
                   (c10l * (1.f - wy) + c11l * wy) * wx;
        float c00h = bf_hi(a000[u]) * (1.f - wz) + bf_hi(a001[u]) * wz;
        float c01h = bf_hi(a010[u]) * (1.f - wz) + bf_hi(a011[u]) * wz;
        float c10h = bf_hi(a100[u]) * (1.f - wz) + bf_hi(a101[u]) * wz;
        float c11h = bf_hi(a110[u]) * (1.f - wz) + bf_hi(a111[u]) * wz;
        r[2 * u + 1] = (c00h * (1.f - wy) + c01h * wy) * (1.f - wx) +
                       (c10h * (1.f - wy) + c11h * wy) * wx;
    }
    unsigned int* row = feats + (size_t)v * 16;
    uint4 o;
    o.x = bf16_pack2(r[0], r[1]); o.y = bf16_pack2(r[2], r[3]);
    o.z = bf16_pack2(r[4], r[5]); o.w = bf16_pack2(r[6], r[7]);
    *(uint4*)(row + q * 4) = o;
    if (q == 0) {
        uint4 o2;
        o2.x = bf16_pack2(px * (1.0f / 128.0f), py * (1.0f / 128.0f));
        o2.y = bf16_pack2(pz * (1.0f / 128.0f), 0.0f);
        o2.z = 0u; o2.w = 0u;
        *(uint4*)(row + 8) = o2;
        *(uint4*)(row + 12) = make_uint4(0u, 0u, 0u, 0u);
    }
}

// ---------------------------------------------------------------------------
// FUSED gather + MFMA edge-conv (bf16 gather; B-fragments from GLOBAL btab).
//   nb_s[vloc][*] = bf16( invdeg[v] * sum_{s in N(v)} x[s][*] )   (LDS tile)
//   out = leakyrelu([x | nb] @ [[Ws],[Wn]] + b)
// LDS = nb_s only -> 8 blocks/CU for latency hiding.
// A frag: lane row = l&15, 8 contiguous k at (l>>4)*8 (16B load).
// B frag: global load from fragment-ready btab (L2-hot 28.7KB table).
// D: col = lane&15, row = (lane>>4)*4 + reg  [m89-verified mapping].
// PREMUL (layer 2): emit z = act(h3) @ Wn3 via 16-lane shfl reduce.
template <int KX, int COUT, bool PREMUL>
__global__ __launch_bounds__(256) void k_layer_fused(const unsigned int* __restrict__ x,
                                                     const unsigned short* __restrict__ btab,
                                                     const int* __restrict__ rowStart,
                                                     const int* __restrict__ csrSrc,
                                                     const float* __restrict__ invdeg,
                                                     const float* __restrict__ bias,
                                                     unsigned int* __restrict__ out, int nv,
                                                     const float* __restrict__ Wn3,
                                                     unsigned int* __restrict__ zout) {
    constexpr int KTOT = 2 * KX;
    constexpr int NT = COUT / 16;     // n-tiles per wave
    constexpr int MT = 2;             // m-tiles per wave (32 vertices)
    constexpr int SXU = KX / 2;       // x row stride in uints
    constexpr int KS = KX / 32;       // k-steps per source
    constexpr int VPB = 128;          // vertices per block
    constexpr int NCH = KX / 8;       // 16B chunks per gathered row
    constexpr int NBW = KX + 8;       // nb_s row stride (bf16); 2-way bank alias (free)
    __shared__ __align__(16) unsigned short nb_s[VPB * NBW];

    // Gather phase: accumulate neighbor rows in registers, write bf16 to LDS.
    const int vb0 = blockIdx.x * VPB;
    for (int task = threadIdx.x; task < VPB * NCH; task += 256) {
        const int vloc = task / NCH;
        const int ch = task - vloc * NCH;
        const int v = vb0 + vloc;
        unsigned short* dst = nb_s + vloc * NBW + ch * 8;
        if (v < nv) {
            int beg = rowStart[v];
            int end = rowStart[v + 1];
            float a0 = 0.f, a1 = 0.f, a2 = 0.f, a3 = 0.f,
                  a4 = 0.f, a5 = 0.f, a6 = 0.f, a7 = 0.f;
            int j = beg;
            for (; j + 3 < end; j += 4) {
                int s0 = csrSrc[j];
                int s1 = csrSrc[j + 1];
                int s2 = csrSrc[j + 2];
                int s3 = csrSrc[j + 3];
                uint4 q0 = ((const uint4*)(x + (size_t)s0 * SXU))[ch];
                uint4 q1 = ((const uint4*)(x + (size_t)s1 * SXU))[ch];
                uint4 q2 = ((const uint4*)(x + (size_t)s2 * SXU))[ch];
                uint4 q3 = ((const uint4*)(x + (size_t)s3 * SXU))[ch];
                a0 += bf_lo(q0.x); a1 += bf_hi(q0.x);
                a2 += bf_lo(q0.y); a3 += bf_hi(q0.y);
                a4 += bf_lo(q0.z); a5 += bf_hi(q0.z);
                a6 += bf_lo(q0.w); a7 += bf_hi(q0.w);
                a0 += bf_lo(q1.x); a1 += bf_hi(q1.x);
                a2 += bf_lo(q1.y); a3 += bf_hi(q1.y);
                a4 += bf_lo(q1.z); a5 += bf_hi(q1.z);
                a6 += bf_lo(q1.w); a7 += bf_hi(q1.w);
                a0 += bf_lo(q2.x); a1 += bf_hi(q2.x);
                a2 += bf_lo(q2.y); a3 += bf_hi(q2.y);
                a4 += bf_lo(q2.z); a5 += bf_hi(q2.z);
                a6 += bf_lo(q2.w); a7 += bf_hi(q2.w);
                a0 += bf_lo(q3.x); a1 += bf_hi(q3.x);
                a2 += bf_lo(q3.y); a3 += bf_hi(q3.y);
                a4 += bf_lo(q3.z); a5 += bf_hi(q3.z);
                a6 += bf_lo(q3.w); a7 += bf_hi(q3.w);
            }
            for (; j < end; ++j) {
                int s = csrSrc[j];
                uint4 q = ((const uint4*)(x + (size_t)s * SXU))[ch];
                a0 += bf_lo(q.x); a1 += bf_hi(q.x);
                a2 += bf_lo(q.y); a3 += bf_hi(q.y);
                a4 += bf_lo(q.z); a5 += bf_hi(q.z);
                a6 += bf_lo(q.w); a7 += bf_hi(q.w);
            }
            const float id = invdeg[v];
            uint4 o;
            o.x = bf16_pack2(a0 * id, a1 * id); o.y = bf16_pack2(a2 * id, a3 * id);
            o.z = bf16_pack2(a4 * id, a5 * id); o.w = bf16_pack2(a6 * id, a7 * id);
            *(uint4*)dst = o;
        } else {
            *(uint4*)dst = make_uint4(0u, 0u, 0u, 0u);
        }
    }
    __syncthreads();

    const int lane = threadIdx.x & 63;
    const int wid = threadIdx.x >> 6;
    const int v0 = vb0 + wid * (MT * 16);
    const int row = lane & 15;
    const int kg = lane >> 4;         // k-subgroup: 8 contiguous k at kg*8

    f4_t acc[MT][NT] = {};

    #pragma unroll
    for (int ks = 0; ks < 2 * KS; ++ks) {
        bf8_t afrag[MT];
        if (ks < KS) {
            const int kbase = ks * 32;
            #pragma unroll
            for (int mt = 0; mt < MT; ++mt) {
                int v = v0 + mt * 16 + row;
                v = min(v, nv - 1);   // clamp: duplicate row, masked at store
                afrag[mt] = *(const bf8_t*)(x + (size_t)v * SXU + ((kbase + kg * 8) >> 1));
            }
        } else {
            const int kbase = (ks - KS) * 32;
            #pragma unroll
            for (int mt = 0; mt < MT; ++mt) {
                const int vloc = wid * (MT * 16) + mt * 16 + row;
                afrag[mt] = *(const bf8_t*)(nb_s + vloc * NBW + kbase + kg * 8);
            }
        }
        #pragma unroll
        for (int nt = 0; nt < NT; ++nt) {
            bf8_t bfrag = *(const bf8_t*)(btab + (nt * 16 + row) * KTOT + ks * 32 + kg * 8);
            #pragma unroll
            for (int mt = 0; mt < MT; ++mt)
                acc[mt][nt] = __builtin_amdgcn_mfma_f32_16x16x32_bf16(afrag[mt], bfrag,
                                                                      acc[mt][nt], 0, 0, 0);
        }
    }

    // Epilogue: bias + leaky relu, bf16 2B stores; optional fused premul.
    unsigned short* po = (unsigned short*)out;
    float bq[NT];
    #pragma unroll
    for (int nt = 0; nt < NT; ++nt) bq[nt] = bias[nt * 16 + row];
    float wz[PREMUL ? NT : 1][3];
    if constexpr (PREMUL) {
        #pragma unroll
        for (int nt = 0; nt < NT; ++nt) {
            const float* wr = Wn3 + (nt * 16 + row) * 3;
            wz[nt][0] = wr[0]; wz[nt][1] = wr[1]; wz[nt][2] = wr[2];
        }
    }
    #pragma unroll
    for (int mt = 0; mt < MT; ++mt) {
        #pragma unroll
        for (int r = 0; r < 4; ++r) {
            const int v = v0 + mt * 16 + kg * 4 + r;
            float tv[NT];
            #pragma unroll
            for (int nt = 0; nt < NT; ++nt) {
                float t = acc[mt][nt][r] + bq[nt];
                t = (t >= 0.f) ? t : SLOPE * t;
                tv[nt] = t;
                if (v < nv) po[(size_t)v * COUT + nt * 16 + row] = bf16_1(t);
            }
            if constexpr (PREMUL) {
                float z0 = 0.f, z1 = 0.f, z2 = 0.f;
                #pragma unroll
                for (int nt = 0; nt < NT; ++nt) {
                    z0 += tv[nt] * wz[nt][0];
                    z1 += tv[nt] * wz[nt][1];
                    z2 += tv[nt] * wz[nt][2];
                }
                #pragma unroll
                for (int m = 1; m < 16; m <<= 1) {
                    z0 += __shfl_xor(z0, m);
                    z1 += __shfl_xor(z1, m);
                    z2 += __shfl_xor(z2, m);
                }
                if (row == 0 && v < nv) {
                    uint2 o;
                    o.x = bf16_pack2(z0, z1);
                    o.y = bf16_pack2(z2, 0.f);
                    *(uint2*)(zout + (size_t)v * 2) = o;
                }
            }
        }
    }
}

// Final (fused z-gather): out = verts + SCALE*(h3@Ws3 + gather(z)*inv_deg + b3)
__global__ __launch_bounds__(256) void k_final(const unsigned int* __restrict__ h,
                                               const unsigned int* __restrict__ z,
                                               const int* __restrict__ rowStart,
                                               const int* __restrict__ csrSrc,
                                               const float* __restrict__ invdeg,
                                               const float* __restrict__ ws,
                                               const float* __restrict__ b,
                                               const float* __restrict__ verts,
                                               float* __restrict__ out, int nv) {
    __shared__ float w_s[64 * 3];
    if (threadIdx.x < 64 * 3) w_s[threadIdx.x] = ws[threadIdx.x];
    __syncthreads();
    int v = blockIdx.x * 256 + threadIdx.x;
    if (v >= nv) return;
    float n0 = 0.f, n1 = 0.f, n2 = 0.f;
    {
        int beg = rowStart[v];
        int end = rowStart[v + 1];
        int j = beg;
        for (; j + 3 < end; j += 4) {
            int s0 = csrSrc[j];
            int s1 = csrSrc[j + 1];
            int s2 = csrSrc[j + 2];
            int s3 = csrSrc[j + 3];
            uint2 q0 = *(const uint2*)(z + (size_t)s0 * 2);
            uint2 q1 = *(const uint2*)(z + (size_t)s1 * 2);
            uint2 q2 = *(const uint2*)(z + (size_t)s2 * 2);
            uint2 q3 = *(const uint2*)(z + (size_t)s3 * 2);
            n0 += bf_lo(q0.x); n1 += bf_hi(q0.x); n2 += bf_lo(q0.y);
            n0 += bf_lo(q1.x); n1 += bf_hi(q1.x); n2 += bf_lo(q1.y);
            n0 += bf_lo(q2.x); n1 += bf_hi(q2.x); n2 += bf_lo(q2.y);
            n0 += bf_lo(q3.x); n1 += bf_hi(q3.x); n2 += bf_lo(q3.y);
        }
        for (; j < end; ++j) {
            int s = csrSrc[j];
            uint2 q = *(const uint2*)(z + (size_t)s * 2);
            n0 += bf_lo(q.x); n1 += bf_hi(q.x); n2 += bf_lo(q.y);
        }
    }
    const uint4* hr = (const uint4*)(h + (size_t)v * 32);
    float a0 = b[0], a1 = b[1], a2 = b[2];
    #pragma unroll
    for (int q = 0; q < 8; ++q) {
        uint4 hv = hr[q];
        float f[8] = {bf_lo(hv.x), bf_hi(hv.x), bf_lo(hv.y), bf_hi(hv.y),
                      bf_lo(hv.z), bf_hi(hv.z), bf_lo(hv.w), bf_hi(hv.w)};
        #pragma unroll
        for (int i = 0; i < 8; ++i) {
            int k = q * 8 + i;
            a0 += f[i] * w_s[k * 3 + 0];
            a1 += f[i] * w_s[k * 3 + 1];
            a2 += f[i] * w_s[k * 3 + 2];
        }
    }
    float id = invdeg[v];
    a0 += n0 * id; a1 += n1 * id; a2 += n2 * id;
    out[(size_t)v * 3 + 0] = verts[(size_t)v * 3 + 0] + SCALE * a0;
    out[(size_t)v * 3 + 1] = verts[(size_t)v * 3 + 1] + SCALE * a1;
    out[(size_t)v * 3 + 2] = verts[(size_t)v * 3 + 2] + SCALE * a2;
}

// ---------------------------------------------------------------------------
extern "C" void kernel_launch(void* const* d_in, const int* in_sizes, int n_in,
                              void* d_out, int out_size, void* d_ws, size_t ws_size,
                              hipStream_t stream) {
    const float* img   = (const float*)d_in[0];
    const float* verts = (const float*)d_in[1];
    const int*   esrc  = (const int*)d_in[2];
    const int*   edst  = (const int*)d_in[3];
    const float* ws0 = (const float*)d_in[4];
    const float* wn0 = (const float*)d_in[5];
    const float* b0  = (const float*)d_in[6];
    const float* ws1 = (const float*)d_in[7];
    const float* wn1 = (const float*)d_in[8];
    const float* b1  = (const float*)d_in[9];
    const float* ws2 = (const float*)d_in[10];
    const float* wn2 = (const float*)d_in[11];
    const float* b2  = (const float*)d_in[12];
    const float* ws3 = (const float*)d_in[13];
    const float* wn3 = (const float*)d_in[14];
    const float* b3  = (const float*)d_in[15];

    const int nv = in_sizes[1] / 3;
    const int ne = in_sizes[2];

    char* base = (char*)d_ws;
    size_t off = 0;
    auto alloc = [&](size_t bytes) -> void* {
        off = (off + 255) & ~(size_t)255;
        void* p = base + off;
        off += bytes;
        return p;
    };
    float* invdeg   = (float*)alloc((size_t)nv * 4);
    int*   rowStart = (int*)alloc((size_t)(nv + 1) * 4);
    int*   bucketCursor = (int*)alloc(256 * 4);
    int*   csrSrc   = (int*)alloc((size_t)ne * 4);
    unsigned int* pairs = (unsigned int*)alloc((size_t)256 * CAPB * 4);
    unsigned int* A   = (unsigned int*)alloc((size_t)nv * 32 * 4);  // feats(16u) then h2(32u)
    unsigned int* B   = (unsigned int*)alloc((size_t)nv * 32 * 4);  // h1(16u) then h3(32u)
    unsigned int* Z   = (unsigned int*)alloc((size_t)nv * 2 * 4);   // bf16 premultiplied
    unsigned short* btab = (unsigned short*)alloc(BT_TOTAL * 2);    // fragment-ready weights
    unsigned int* timg = (unsigned int*)alloc((size_t)VOL * 16 * 2);

    auto blocks = [](long long n) { return (int)((n + 255) / 256); };
    const int nbuckets = (nv + 511) >> 9;
    const int lb = (nv + 127) / 128;  // fused layers: 128 vertices per block

    hipMemsetAsync(bucketCursor, 0, 256 * 4, stream);
    k_prepw<<<(BT_TOTAL + 255) / 256, 256, 0, stream>>>(ws0, wn0, ws1, wn1, ws2, wn2, btab);
    k_transpose<<<GRIDSZ * GRIDSZ, 256, 0, stream>>>(img, timg);
    k_bucket<<<(ne + EPB - 1) / EPB, 256, 0, stream>>>(esrc, edst, bucketCursor,
                                                       pairs, rowStart, ne, nv);
    k_binsort<<<nbuckets, 256, 0, stream>>>(pairs, bucketCursor, rowStart, invdeg, csrSrc, nv);

    // Features (channel-last bf16 volume) -> bf16 feats
    k_sample<<<blocks((long long)nv * 2), 256, 0, stream>>>(timg, verts, A, nv);

    // Layer 0: 19 -> 32 (feats stride 16u, KX=32)
    k_layer_fused<32, 32, false><<<lb, 256, 0, stream>>>(
        A, btab + BT0_OFF, rowStart, csrSrc, invdeg, b0, B, nv, nullptr, nullptr);

    // Layer 1: 32 -> 64 (h1 stride 16u, KX=32)
    k_layer_fused<32, 64, false><<<lb, 256, 0, stream>>>(
        B, btab + BT1_OFF, rowStart, csrSrc, invdeg, b1, A, nv, nullptr, nullptr);

    // Layer 2: 64 -> 64 (h2 stride 32u, KX=64), fused premul z = h3 @ Wn3
    k_layer_fused<64, 64, true><<<lb, 256, 0, stream>>>(
        A, btab + BT2_OFF, rowStart, csrSrc, invdeg, b2, B, nv, wn3, Z);

    // Layer 3: fused gather+final update
    k_final<<<blocks(nv), 256, 0, stream>>>(
        B, Z, rowStart, csrSrc, invdeg, ws3, b3, verts, (float*)d_out, nv);
}

// Round 8
// 400.620 us; speedup vs baseline: 1.2415x; 1.0393x over previous
//
#include <hip/hip_runtime.h>

// Problem constants (from reference)
#define C_IMG 16
#define GRIDSZ 128
#define VOL (GRIDSZ * GRIDSZ * GRIDSZ)
#define SLOPE 0.3f
#define SCALE 0.1f
#define EPB 4096         // edges per bucket block
#define CAPB 12288       // fixed pair-region capacity per 512-vtx bucket (mean 8192, sd ~90)
#define BIN_CAP 16384    // binsort LDS staging capacity

// btab offsets (bf16 elems): L0 = 32x64, L1 = 64x64, L2 = 64x128
#define BT0_OFF 0
#define BT1_OFF 2048
#define BT2_OFF 6144
#define BT_TOTAL 14336
#define PREPW_BLOCKS ((BT_TOTAL + 255) / 256)

using f4_t  = __attribute__((ext_vector_type(4))) float;
using bf8_t = __attribute__((ext_vector_type(8))) short;

// bf16 helpers (manual, RNE pack / shift unpack)
__device__ __forceinline__ unsigned int bf16_pack2(float a, float b) {
    unsigned int ua = __float_as_uint(a);
    ua = (ua + 0x7FFFu + ((ua >> 16) & 1u)) >> 16;
    unsigned int ub = __float_as_uint(b);
    ub = (ub + 0x7FFFu + ((ub >> 16) & 1u)) >> 16;
    return ua | (ub << 16);
}
__device__ __forceinline__ unsigned short bf16_1(float a) {
    unsigned int ua = __float_as_uint(a);
    return (unsigned short)((ua + 0x7FFFu + ((ua >> 16) & 1u)) >> 16);
}
__device__ __forceinline__ float bf_lo(unsigned int u) { return __uint_as_float(u << 16); }
__device__ __forceinline__ float bf_hi(unsigned int u) { return __uint_as_float(u & 0xFFFF0000u); }

// ---------------------------------------------------------------------------
// Fused front-end (independent works, grid-partitioned):
//   blocks [0, nbb)                      : bucket pass (edges -> per-bucket pair regions)
//   blocks [nbb, nbb+PREPW_BLOCKS)       : weight prep into btab
//   blocks [nbb+PREPW_BLOCKS, ...)       : image transpose
// Bucket (~30us) and prepw hide under the transpose stream; saves 2 launch gaps.
__global__ __launch_bounds__(256) void k_pre(const float* __restrict__ img,
                                             unsigned int* __restrict__ timg,
                                             const float* __restrict__ ws0,
                                             const float* __restrict__ wn0,
                                             const float* __restrict__ ws1,
                                             const float* __restrict__ wn1,
                                             const float* __restrict__ ws2,
                                             const float* __restrict__ wn2,
                                             unsigned short* __restrict__ btab,
                                             const int* __restrict__ esrc,
                                             const int* __restrict__ edst,
                                             int* __restrict__ bucketCursor,
                                             unsigned int* __restrict__ pairs,
                                             int* __restrict__ rowStart,
                                             int ne, int nv, int nbb) {
    __shared__ unsigned int hist[256];
    __shared__ unsigned int pref[256];
    __shared__ unsigned int curs[256];
    __shared__ unsigned int gbase[256];
    __shared__ unsigned int stage_v[EPB];
    __shared__ unsigned char stage_b[EPB];
    const int tid = threadIdx.x;

    if (blockIdx.x < (unsigned)nbb) {
        // ---- bucket pass: packed pair (src<<9)|(dst&511), src < 2^17 ----
        const int base = blockIdx.x * EPB;
        const int n = min(EPB, ne - base);
        if (blockIdx.x == 0 && tid == 0) rowStart[nv] = ne;
        hist[tid] = 0;
        __syncthreads();
        for (int i = tid; i < n; i += 256)
            atomicAdd(&hist[((unsigned)edst[base + i]) >> 9], 1u);
        __syncthreads();
        const unsigned int h = hist[tid];
        pref[tid] = h;
        __syncthreads();
        #pragma unroll
        for (int off = 1; off < 256; off <<= 1) {
            unsigned int t = (tid >= off) ? pref[tid - off] : 0;
            __syncthreads();
            pref[tid] += t;
            __syncthreads();
        }
        const unsigned int excl = pref[tid] - h;
        if (h) {
            int pos = atomicAdd(&bucketCursor[tid], (int)h);
            if (pos > CAPB - (int)h) pos = CAPB - (int)h;  // statistically unreachable guard
            gbase[tid] = (unsigned int)(tid * CAPB + pos);
        } else {
            gbase[tid] = 0u;
        }
        __syncthreads();
        pref[tid] = excl;
        curs[tid] = excl;
        __syncthreads();
        for (int i = tid; i < n; i += 256) {
            unsigned int d = (unsigned)edst[base + i];
            unsigned int s = (unsigned)esrc[base + i];
            unsigned int p = atomicAdd(&curs[d >> 9], 1u);
            stage_v[p] = (s << 9) | (d & 511u);
            stage_b[p] = (unsigned char)(d >> 9);
        }
        __syncthreads();
        for (int i = tid; i < n; i += 256) {
            unsigned int b = stage_b[i];
            pairs[gbase[b] + (unsigned)i - pref[b]] = stage_v[i];
        }
    } else if (blockIdx.x < (unsigned)(nbb + PREPW_BLOCKS)) {
        // ---- weight prep ----
        int i = (blockIdx.x - nbb) * 256 + tid;
        if (i < 2048) {                       // L0: COUT=32, KTOT=64, remap, valid 19
            int c = i >> 6, kk = i & 63;
            int j = (kk < 32) ? kk : kk - 32;
            const float* W = (kk < 32) ? ws0 : wn0;
            float w = 0.f;
            if (j < 19) { int sr = (j < 16) ? (j + 3) : (j - 16); w = W[sr * 32 + c]; }
            btab[BT0_OFF + c * 64 + kk] = bf16_1(w);
        } else if (i < 6144) {                // L1: COUT=64, KTOT=64
            int t = i - 2048;
            int c = t >> 6, kk = t & 63;
            int j = (kk < 32) ? kk : kk - 32;
            const float* W = (kk < 32) ? ws1 : wn1;
            btab[BT1_OFF + c * 64 + kk] = bf16_1(W[j * 64 + c]);
        } else if (i < BT_TOTAL) {            // L2: COUT=64, KTOT=128
            int t = i - 6144;
            int c = t >> 7, kk = t & 127;
            int j = (kk < 64) ? kk : kk - 64;
            const float* W = (kk < 64) ? ws2 : wn2;
            btab[BT2_OFF + c * 128 + kk] = bf16_1(W[j * 64 + c]);
        }
    } else {
        // ---- transpose: one thread = one 16B output chunk, 8 independent 4B loads ----
        const int xy = blockIdx.x - nbb - PREPW_BLOCKS;   // x*128+y
        const int zlo = tid & 31;
        const int half = (tid >> 5) & 1;
        const int zhi = tid >> 6;
        const int z = zhi * 32 + zlo;
        const size_t ib = (size_t)xy * GRIDSZ + z;
        const int c0 = half * 8;
        float f[8];
        #pragma unroll
        for (int c = 0; c < 8; ++c)
            f[c] = img[(size_t)(c0 + c) * VOL + ib];
        uint4 o;
        o.x = bf16_pack2(f[0], f[1]);
        o.y = bf16_pack2(f[2], f[3]);
        o.z = bf16_pack2(f[4], f[5]);
        o.w = bf16_pack2(f[6], f[7]);
        *(uint4*)(timg + ((size_t)xy * GRIDSZ + z) * 8 + half * 4) = o;
    }
}

// Within-bucket sort -> dense csrSrc + rowStart + invdeg.
__global__ __launch_bounds__(256) void k_binsort(const unsigned int* __restrict__ pairs,
                                                 const int* __restrict__ bucketCursor,
                                                 int* __restrict__ rowStart,
                                                 float* __restrict__ invdeg,
                                                 int* __restrict__ csrSrc, int nv) {
    __shared__ int deg_s[512];
    __shared__ int rs_s[512];
    __shared__ int cur_s[512];
    __shared__ int scan_s[256];
    __shared__ int bb[256];
    __shared__ int outbuf[BIN_CAP];
    const int tid = threadIdx.x;
    const int b = blockIdx.x;
    const int vbase = b << 9;
    if (vbase >= nv) return;
    const int nvb = min(512, nv - vbase);
    const int c = min(bucketCursor[tid], CAPB);
    bb[tid] = c;
    deg_s[tid] = 0;
    deg_s[tid + 256] = 0;
    __syncthreads();
    #pragma unroll
    for (int off = 1; off < 256; off <<= 1) {
        int t = (tid >= off) ? bb[tid - off] : 0;
        __syncthreads();
        bb[tid] += t;
        __syncthreads();
    }
    const int count = min(bucketCursor[b], CAPB);
    const int gs = bb[b] - count;
    const unsigned int* pbase = pairs + (size_t)b * CAPB;
    for (int i = tid; i < count; i += 256) {
        unsigned int p = pbase[i];
        atomicAdd(&deg_s[p & 511u], 1);
    }
    __syncthreads();
    const int d0 = deg_s[2 * tid];
    const int d1 = deg_s[2 * tid + 1];
    const int ps = d0 + d1;
    scan_s[tid] = ps;
    __syncthreads();
    #pragma unroll
    for (int off = 1; off < 256; off <<= 1) {
        int t = (tid >= off) ? scan_s[tid - off] : 0;
        __syncthreads();
        scan_s[tid] += t;
        __syncthreads();
    }
    const int epair = scan_s[tid] - ps;
    rs_s[2 * tid] = epair;
    rs_s[2 * tid + 1] = epair + d0;
    cur_s[2 * tid] = epair;
    cur_s[2 * tid + 1] = epair + d0;
    #pragma unroll
    for (int u = 0; u < 2; ++u) {
        int idx = 2 * tid + u;
        if (idx < nvb) {
            rowStart[vbase + idx] = gs + rs_s[idx];
            int d = deg_s[idx];
            invdeg[vbase + idx] = 1.0f / (float)(d > 1 ? d : 1);
        }
    }
    __syncthreads();
    for (int i = tid; i < count; i += 256) {
        unsigned int p = pbase[i];
        int pos = atomicAdd(&cur_s[p & 511u], 1);
        outbuf[pos] = (int)(p >> 9);
    }
    __syncthreads();
    for (int i = tid; i < count; i += 256) csrSrc[gs + i] = outbuf[i];
}

// ---------------------------------------------------------------------------
// Trilinear sample -> bf16 feats rows, stride 16 uints (32 bf16 cols):
// cols 0..15 = channels, 16..18 = verts/128, 19..31 = 0.
__global__ __launch_bounds__(256) void k_sample(const unsigned int* __restrict__ timg,
                                                const float* __restrict__ verts,
                                                unsigned int* __restrict__ feats, int nv) {
    int t = blockIdx.x * 256 + threadIdx.x;
    int v = t >> 1;
    int q = t & 1;          // channel group: q*8 .. q*8+7
    if (v >= nv) return;
    float px = verts[v * 3 + 0];
    float py = verts[v * 3 + 1];
    float pz = verts[v * 3 + 2];
    float cx = fminf(fmaxf(px, 0.0f), 127.0f);
    float cy = fminf(fmaxf(py, 0.0f), 127.0f);
    float cz = fminf(fmaxf(pz, 0.0f), 127.0f);
    float fx = floorf(cx), fy = floorf(cy), fz = floorf(cz);
    int x0 = (int)fx, y0 = (int)fy, z0 = (int)fz;
    int x1 = min(x0 + 1, 127), y1 = min(y0 + 1, 127), z1 = min(z0 + 1, 127);
    float wx = cx - fx, wy = cy - fy, wz = cz - fz;
    const int qo = q * 4;
    #define LD(X, Y, Z) (*(const uint4*)(timg + ((size_t)((((X) << 7) + (Y)) << 7) + (size_t)(Z)) * 8 + qo))
    uint4 f000 = LD(x0, y0, z0), f001 = LD(x0, y0, z1);
    uint4 f010 = LD(x0, y1, z0), f011 = LD(x0, y1, z1);
    uint4 f100 = LD(x1, y0, z0), f101 = LD(x1, y0, z1);
    uint4 f110 = LD(x1, y1, z0), f111 = LD(x1, y1, z1);
    #undef LD
    float r[8];
    const unsigned int* a000 = (const unsigned int*)&f000;
    const unsigned int* a001 = (const unsigned int*)&f001;
    const unsigned int* a010 = (const unsigned int*)&f010;
    const unsigned int* a011 = (const unsigned int*)&f011;
    const unsigned int* a100 = (const unsigned int*)&f100;
    const unsigned int* a101 = (const unsigned int*)&f101;
    const unsigned int* a110 = (const unsigned int*)&f110;
    const unsigned int* a111 = (const unsigned int*)&f111;
    #pragma unroll
    for (int u = 0; u < 4; ++u) {
        float c00l = bf_lo(a000[u]) * (1.f - wz) + bf_lo(a001[u]) * wz;
        float c01l = bf_lo(a010[u]) * (1.f - wz) + bf_lo(a011[u]) * wz;
        float c10l = bf_lo(a100[u]) * (1.f - wz) + bf_lo(a101[u]) * wz;
        float c11l = bf_lo(a110[u]) * (1.f - wz) + bf_lo(a111[u]) * wz;
        r[2 * u] = (c00l * (1.f - wy) + c01l * wy) * (1.f - wx) +
                   (c10l * (1.f - wy) + c11l * wy) * wx;
        float c00h = bf_hi(a000[u]) * (1.f - wz) + bf_hi(a001[u]) * wz;
        float c01h = bf_hi(a010[u]) * (1.f - wz) + bf_hi(a011[u]) * wz;
        float c10h = bf_hi(a100[u]) * (1.f - wz) + bf_hi(a101[u]) * wz;
        float c11h = bf_hi(a110[u]) * (1.f - wz) + bf_hi(a111[u]) * wz;
        r[2 * u + 1] = (c00h * (1.f - wy) + c01h * wy) * (1.f - wx) +
                       (c10h * (1.f - wy) + c11h * wy) * wx;
    }
    unsigned int* row = feats + (size_t)v * 16;
    uint4 o;
    o.x = bf16_pack2(r[0], r[1]); o.y = bf16_pack2(r[2], r[3]);
    o.z = bf16_pack2(r[4], r[5]); o.w = bf16_pack2(r[6], r[7]);
    *(uint4*)(row + q * 4) = o;
    if (q == 0) {
        uint4 o2;
        o2.x = bf16_pack2(px * (1.0f / 128.0f), py * (1.0f / 128.0f));
        o2.y = bf16_pack2(pz * (1.0f / 128.0f), 0.0f);
        o2.z = 0u; o2.w = 0u;
        *(uint4*)(row + 8) = o2;
        *(uint4*)(row + 12) = make_uint4(0u, 0u, 0u, 0u);
    }
}

// ---------------------------------------------------------------------------
// FUSED gather + MFMA edge-conv (bf16 gather; B-fragments from GLOBAL btab).
// DEGREE-BALANCED gather: the 128 vertices are rank-sorted by degree in LDS
// (O(128^2) compares, ~2us/block) and threads process vertices in sorted
// order -> each wave holds similar-degree vertices, removing the ~1.5x
// wave-max-degree inflation of the gather loop (Poisson-16 degrees).
// A frag: lane row = l&15, 8 contiguous k at (l>>4)*8 (16B load).
// B frag: global load from fragment-ready btab (L2-hot 28.7KB table).
// D: col = lane&15, row = (lane>>4)*4 + reg  [m89-verified mapping].
// PREMUL (layer 2): emit z = act(h3) @ Wn3 via 16-lane shfl reduce.
template <int KX, int COUT, bool PREMUL>
__global__ __launch_bounds__(256) void k_layer_fused(const unsigned int* __restrict__ x,
                                                     const unsigned short* __restrict__ btab,
                                                     const int* __restrict__ rowStart,
                                                     const int* __restrict__ csrSrc,
                                                     const float* __restrict__ invdeg,
                                                     const float* __restrict__ bias,
                                                     unsigned int* __restrict__ out, int nv,
                                                     const float* __restrict__ Wn3,
                                                     unsigned int* __restrict__ zout) {
    constexpr int KTOT = 2 * KX;
    constexpr int NT = COUT / 16;     // n-tiles per wave
    constexpr int MT = 2;             // m-tiles per wave (32 vertices)
    constexpr int SXU = KX / 2;       // x row stride in uints
    constexpr int KS = KX / 32;       // k-steps per source
    constexpr int VPB = 128;          // vertices per block
    constexpr int NCH = KX / 8;       // 16B chunks per gathered row
    constexpr int LOG_NCH = (KX == 32) ? 2 : 3;
    constexpr int NBW = KX + 8;       // nb_s row stride (bf16); 2-way bank alias (free)
    __shared__ __align__(16) unsigned short nb_s[VPB * NBW];
    __shared__ int beg_s[VPB];
    __shared__ int end_s[VPB];
    __shared__ unsigned short order_s[VPB];

    const int vb0 = blockIdx.x * VPB;
    const int tid = threadIdx.x;

    // Load row ranges + rank-sort by degree (ties by index -> permutation).
    if (tid < VPB) {
        int v = vb0 + tid;
        int b = 0, e = 0;
        if (v < nv) { b = rowStart[v]; e = rowStart[v + 1]; }
        beg_s[tid] = b;
        end_s[tid] = e;
    }
    __syncthreads();
    if (tid < VPB) {
        const int d = end_s[tid] - beg_s[tid];
        int rank = 0;
        #pragma unroll 4
        for (int j = 0; j < VPB; ++j) {
            int dj = end_s[j] - beg_s[j];
            rank += (dj < d) || (dj == d && j < tid);
        }
        order_s[rank] = (unsigned short)tid;
    }
    __syncthreads();

    // Gather phase: degree-sorted thread->vertex assignment.
    for (int task = tid; task < VPB * NCH; task += 256) {
        const int srt = task >> LOG_NCH;
        const int ch = task & (NCH - 1);
        const int vloc = order_s[srt];
        const int v = vb0 + vloc;
        unsigned short* dst = nb_s + vloc * NBW + ch * 8;
        if (v < nv) {
            const int beg = beg_s[vloc];
            const int end = end_s[vloc];
            float a0 = 0.f, a1 = 0.f, a2 = 0.f, a3 = 0.f,
                  a4 = 0.f, a5 = 0.f, a6 = 0.f, a7 = 0.f;
            int j = beg;
            for (; j + 3 < end; j += 4) {
                int s0 = csrSrc[j];
                int s1 = csrSrc[j + 1];
                int s2 = csrSrc[j + 2];
                int s3 = csrSrc[j + 3];
                uint4 q0 = ((const uint4*)(x + (size_t)s0 * SXU))[ch];
                uint4 q1 = ((const uint4*)(x + (size_t)s1 * SXU))[ch];
                uint4 q2 = ((const uint4*)(x + (size_t)s2 * SXU))[ch];
                uint4 q3 = ((const uint4*)(x + (size_t)s3 * SXU))[ch];
                a0 += bf_lo(q0.x); a1 += bf_hi(q0.x);
                a2 += bf_lo(q0.y); a3 += bf_hi(q0.y);
                a4 += bf_lo(q0.z); a5 += bf_hi(q0.z);
                a6 += bf_lo(q0.w); a7 += bf_hi(q0.w);
                a0 += bf_lo(q1.x); a1 += bf_hi(q1.x);
                a2 += bf_lo(q1.y); a3 += bf_hi(q1.y);
                a4 += bf_lo(q1.z); a5 += bf_hi(q1.z);
                a6 += bf_lo(q1.w); a7 += bf_hi(q1.w);
                a0 += bf_lo(q2.x); a1 += bf_hi(q2.x);
                a2 += bf_lo(q2.y); a3 += bf_hi(q2.y);
                a4 += bf_lo(q2.z); a5 += bf_hi(q2.z);
                a6 += bf_lo(q2.w); a7 += bf_hi(q2.w);
                a0 += bf_lo(q3.x); a1 += bf_hi(q3.x);
                a2 += bf_lo(q3.y); a3 += bf_hi(q3.y);
                a4 += bf_lo(q3.z); a5 += bf_hi(q3.z);
                a6 += bf_lo(q3.w); a7 += bf_hi(q3.w);
            }
            for (; j < end; ++j) {
                int s = csrSrc[j];
                uint4 q = ((const uint4*)(x + (size_t)s * SXU))[ch];
                a0 += bf_lo(q.x); a1 += bf_hi(q.x);
                a2 += bf_lo(q.y); a3 += bf_hi(q.y);
                a4 += bf_lo(q.z); a5 += bf_hi(q.z);
                a6 += bf_lo(q.w); a7 += bf_hi(q.w);
            }
            const float id = invdeg[v];
            uint4 o;
            o.x = bf16_pack2(a0 * id, a1 * id); o.y = bf16_pack2(a2 * id, a3 * id);
            o.z = bf16_pack2(a4 * id, a5 * id); o.w = bf16_pack2(a6 * id, a7 * id);
            *(uint4*)dst = o;
        } else {
            *(uint4*)dst = make_uint4(0u, 0u, 0u, 0u);
        }
    }
    __syncthreads();

    const int lane = tid & 63;
    const int wid = tid >> 6;
    const int v0 = vb0 + wid * (MT * 16);
    const int row = lane & 15;
    const int kg = lane >> 4;         // k-subgroup: 8 contiguous k at kg*8

    f4_t acc[MT][NT] = {};

    #pragma unroll
    for (int ks = 0; ks < 2 * KS; ++ks) {
        bf8_t afrag[MT];
        if (ks < KS) {
            const int kbase = ks * 32;
            #pragma unroll
            for (int mt = 0; mt < MT; ++mt) {
                int v = v0 + mt * 16 + row;
                v = min(v, nv - 1);   // clamp: duplicate row, masked at store
                afrag[mt] = *(const bf8_t*)(x + (size_t)v * SXU + ((kbase + kg * 8) >> 1));
            }
        } else {
            const int kbase = (ks - KS) * 32;
            #pragma unroll
            for (int mt = 0; mt < MT; ++mt) {
                const int vloc = wid * (MT * 16) + mt * 16 + row;
                afrag[mt] = *(const bf8_t*)(nb_s + vloc * NBW + kbase + kg * 8);
            }
        }
        #pragma unroll
        for (int nt = 0; nt < NT; ++nt) {
            bf8_t bfrag = *(const bf8_t*)(btab + (nt * 16 + row) * KTOT + ks * 32 + kg * 8);
            #pragma unroll
            for (int mt = 0; mt < MT; ++mt)
                acc[mt][nt] = __builtin_amdgcn_mfma_f32_16x16x32_bf16(afrag[mt], bfrag,
                                                                      acc[mt][nt], 0, 0, 0);
        }
    }

    // Epilogue: bias + leaky relu, bf16 2B stores; optional fused premul.
    unsigned short* po = (unsigned short*)out;
    float bq[NT];
    #pragma unroll
    for (int nt = 0; nt < NT; ++nt) bq[nt] = bias[nt * 16 + row];
    float wz[PREMUL ? NT : 1][3];
    if constexpr (PREMUL) {
        #pragma unroll
        for (int nt = 0; nt < NT; ++nt) {
            const float* wr = Wn3 + (nt * 16 + row) * 3;
            wz[nt][0] = wr[0]; wz[nt][1] = wr[1]; wz[nt][2] = wr[2];
        }
    }
    #pragma unroll
    for (int mt = 0; mt < MT; ++mt) {
        #pragma unroll
        for (int r = 0; r < 4; ++r) {
            const int v = v0 + mt * 16 + kg * 4 + r;
            float tv[NT];
            #pragma unroll
            for (int nt = 0; nt < NT; ++nt) {
                float t = acc[mt][nt][r] + bq[nt];
                t = (t >= 0.f) ? t : SLOPE * t;
                tv[nt] = t;
                if (v < nv) po[(size_t)v * COUT + nt * 16 + row] = bf16_1(t);
            }
            if constexpr (PREMUL) {
                float z0 = 0.f, z1 = 0.f, z2 = 0.f;
                #pragma unroll
                for (int nt = 0; nt < NT; ++nt) {
                    z0 += tv[nt] * wz[nt][0];
                    z1 += tv[nt] * wz[nt][1];
                    z2 += tv[nt] * wz[nt][2];
                }
                #pragma unroll
                for (int m = 1; m < 16; m <<= 1) {
                    z0 += __shfl_xor(z0, m);
                    z1 += __shfl_xor(z1, m);
                    z2 += __shfl_xor(z2, m);
                }
                if (row == 0 && v < nv) {
                    uint2 o;
                    o.x = bf16_pack2(z0, z1);
                    o.y = bf16_pack2(z2, 0.f);
                    *(uint2*)(zout + (size_t)v * 2) = o;
                }
            }
        }
    }
}

// Final (fused z-gather): out = verts + SCALE*(h3@Ws3 + gather(z)*inv_deg + b3)
__global__ __launch_bounds__(256) void k_final(const unsigned int* __restrict__ h,
                                               const unsigned int* __restrict__ z,
                                               const int* __restrict__ rowStart,
                                               const int* __restrict__ csrSrc,
                                               const float* __restrict__ invdeg,
                                               const float* __restrict__ ws,
                                               const float* __restrict__ b,
                                               const float* __restrict__ verts,
                                               float* __restrict__ out, int nv) {
    __shared__ float w_s[64 * 3];
    if (threadIdx.x < 64 * 3) w_s[threadIdx.x] = ws[threadIdx.x];
    __syncthreads();
    int v = blockIdx.x * 256 + threadIdx.x;
    if (v >= nv) return;
    float n0 = 0.f, n1 = 0.f, n2 = 0.f;
    {
        int beg = rowStart[v];
        int end = rowStart[v + 1];
        int j = beg;
        for (; j + 3 < end; j += 4) {
            int s0 = csrSrc[j];
            int s1 = csrSrc[j + 1];
            int s2 = csrSrc[j + 2];
            int s3 = csrSrc[j + 3];
            uint2 q0 = *(const uint2*)(z + (size_t)s0 * 2);
            uint2 q1 = *(const uint2*)(z + (size_t)s1 * 2);
            uint2 q2 = *(const uint2*)(z + (size_t)s2 * 2);
            uint2 q3 = *(const uint2*)(z + (size_t)s3 * 2);
            n0 += bf_lo(q0.x); n1 += bf_hi(q0.x); n2 += bf_lo(q0.y);
            n0 += bf_lo(q1.x); n1 += bf_hi(q1.x); n2 += bf_lo(q1.y);
            n0 += bf_lo(q2.x); n1 += bf_hi(q2.x); n2 += bf_lo(q2.y);
            n0 += bf_lo(q3.x); n1 += bf_hi(q3.x); n2 += bf_lo(q3.y);
        }
        for (; j < end; ++j) {
            int s = csrSrc[j];
            uint2 q = *(const uint2*)(z + (size_t)s * 2);
            n0 += bf_lo(q.x); n1 += bf_hi(q.x); n2 += bf_lo(q.y);
        }
    }
    const uint4* hr = (const uint4*)(h + (size_t)v * 32);
    float a0 = b[0], a1 = b[1], a2 = b[2];
    #pragma unroll
    for (int q = 0; q < 8; ++q) {
        uint4 hv = hr[q];
        float f[8] = {bf_lo(hv.x), bf_hi(hv.x), bf_lo(hv.y), bf_hi(hv.y),
                      bf_lo(hv.z), bf_hi(hv.z), bf_lo(hv.w), bf_hi(hv.w)};
        #pragma unroll
        for (int i = 0; i < 8; ++i) {
            int k = q * 8 + i;
            a0 += f[i] * w_s[k * 3 + 0];
            a1 += f[i] * w_s[k * 3 + 1];
            a2 += f[i] * w_s[k * 3 + 2];
        }
    }
    float id = invdeg[v];
    a0 += n0 * id; a1 += n1 * id; a2 += n2 * id;
    out[(size_t)v * 3 + 0] = verts[(size_t)v * 3 + 0] + SCALE * a0;
    out[(size_t)v * 3 + 1] = verts[(size_t)v * 3 + 1] + SCALE * a1;
    out[(size_t)v * 3 + 2] = verts[(size_t)v * 3 + 2] + SCALE * a2;
}

// ---------------------------------------------------------------------------
extern "C" void kernel_launch(void* const* d_in, const int* in_sizes, int n_in,
                              void* d_out, int out_size, void* d_ws, size_t ws_size,
                              hipStream_t stream) {
    const float* img   = (const float*)d_in[0];
    const float* verts = (const float*)d_in[1];
    const int*   esrc  = (const int*)d_in[2];
    const int*   edst  = (const int*)d_in[3];
    const float* ws0 = (const float*)d_in[4];
    const float* wn0 = (const float*)d_in[5];
    const float* b0  = (const float*)d_in[6];
    const float* ws1 = (const float*)d_in[7];
    const float* wn1 = (const float*)d_in[8];
    const float* b1  = (const float*)d_in[9];
    const float* ws2 = (const float*)d_in[10];
    const float* wn2 = (const float*)d_in[11];
    const float* b2  = (const float*)d_in[12];
    const float* ws3 = (const float*)d_in[13];
    const float* wn3 = (const float*)d_in[14];
    const float* b3  = (const float*)d_in[15];

    const int nv = in_sizes[1] / 3;
    const int ne = in_sizes[2];

    char* base = (char*)d_ws;
    size_t off = 0;
    auto alloc = [&](size_t bytes) -> void* {
        off = (off + 255) & ~(size_t)255;
        void* p = base + off;
        off += bytes;
        return p;
    };
    float* invdeg   = (float*)alloc((size_t)nv * 4);
    int*   rowStart = (int*)alloc((size_t)(nv + 1) * 4);
    int*   bucketCursor = (int*)alloc(256 * 4);
    int*   csrSrc   = (int*)alloc((size_t)ne * 4);
    unsigned int* pairs = (unsigned int*)alloc((size_t)256 * CAPB * 4);
    unsigned int* A   = (unsigned int*)alloc((size_t)nv * 32 * 4);  // feats(16u) then h2(32u)
    unsigned int* B   = (unsigned int*)alloc((size_t)nv * 32 * 4);  // h1(16u) then h3(32u)
    unsigned int* Z   = (unsigned int*)alloc((size_t)nv * 2 * 4);   // bf16 premultiplied
    unsigned short* btab = (unsigned short*)alloc(BT_TOTAL * 2);    // fragment-ready weights
    unsigned int* timg = (unsigned int*)alloc((size_t)VOL * 16 * 2);

    auto blocks = [](long long n) { return (int)((n + 255) / 256); };
    const int nbuckets = (nv + 511) >> 9;
    const int nbb = (ne + EPB - 1) / EPB;
    const int lb = (nv + 127) / 128;  // fused layers: 128 vertices per block

    hipMemsetAsync(bucketCursor, 0, 256 * 4, stream);
    // Fused front-end: bucket || prepw || transpose
    k_pre<<<nbb + PREPW_BLOCKS + GRIDSZ * GRIDSZ, 256, 0, stream>>>(
        img, timg, ws0, wn0, ws1, wn1, ws2, wn2, btab,
        esrc, edst, bucketCursor, pairs, rowStart, ne, nv, nbb);
    k_binsort<<<nbuckets, 256, 0, stream>>>(pairs, bucketCursor, rowStart, invdeg, csrSrc, nv);

    // Features (channel-last bf16 volume) -> bf16 feats
    k_sample<<<blocks((long long)nv * 2), 256, 0, stream>>>(timg, verts, A, nv);

    // Layer 0: 19 -> 32 (feats stride 16u, KX=32)
    k_layer_fused<32, 32, false><<<lb, 256, 0, stream>>>(
        A, btab + BT0_OFF, rowStart, csrSrc, invdeg, b0, B, nv, nullptr, nullptr);

    // Layer 1: 32 -> 64 (h1 stride 16u, KX=32)
    k_layer_fused<32, 64, false><<<lb, 256, 0, stream>>>(
        B, btab + BT1_OFF, rowStart, csrSrc, invdeg, b1, A, nv, nullptr, nullptr);

    // Layer 2: 64 -> 64 (h2 stride 32u, KX=64), fused premul z = h3 @ Wn3
    k_layer_fused<64, 64, true><<<lb, 256, 0, stream>>>(
        A, btab + BT2_OFF, rowStart, csrSrc, invdeg, b2, B, nv, wn3, Z);

    // Layer 3: fused gather+final update
    k_final<<<blocks(nv), 256, 0, stream>>>(
        B, Z, rowStart, csrSrc, invdeg, ws3, b3, verts, (float*)d_out, nv);
}